// Round 1
// baseline (582.469 us; speedup 1.0000x reference)
//
#include <hip/hip_runtime.h>
#include <hip/hip_bf16.h>
#include <stdint.h>

#define NFEAT 32768
#define BATCH 1024
#define DK 64
#define DV 64
#define DD 4096
#define KSEL 32
#define CAND_CAP 512
#define CAND_TARGET 48

using bf16 = __bf16;
using bf16x8 = __attribute__((ext_vector_type(8))) __bf16;
using f32x4 = __attribute__((ext_vector_type(4))) float;

__device__ inline void gload_lds16(const void* g, void* l) {
  __builtin_amdgcn_global_load_lds((const __attribute__((address_space(1))) void*)g,
                                   (__attribute__((address_space(3))) void*)l,
                                   16, 0, 0);
}

__device__ inline unsigned monou(float f) {
  unsigned u = __float_as_uint(f);
  return ((int)u < 0) ? ~u : (u | 0x80000000u);
}

// ---------------- x -> bf16 ----------------
__global__ void k_convert_x(const float* __restrict__ x, bf16* __restrict__ xb, int n) {
  int i = (blockIdx.x * blockDim.x + threadIdx.x) * 8;
  if (i >= n) return;
  float4 v0 = *reinterpret_cast<const float4*>(x + i);
  float4 v1 = *reinterpret_cast<const float4*>(x + i + 4);
  bf16x8 o;
  o[0] = (bf16)v0.x; o[1] = (bf16)v0.y; o[2] = (bf16)v0.z; o[3] = (bf16)v0.w;
  o[4] = (bf16)v1.x; o[5] = (bf16)v1.y; o[6] = (bf16)v1.z; o[7] = (bf16)v1.w;
  *reinterpret_cast<bf16x8*>(xb + i) = o;
}

// ---------------- M_enc[i][k*64+v] = V_enc[i][k] * W_enc[i][v] (bf16) ----------------
__global__ void k_build_menc(const float* __restrict__ Venc, const float* __restrict__ Wenc,
                             bf16* __restrict__ Menc) {
  int i = blockIdx.x;       // feature
  int t = threadIdx.x;      // 256 threads; t -> k=t>>2, vblock=(t&3)*16
  int k = t >> 2;
  int vb = (t & 3) << 4;
  float vk = Venc[i * DK + k];
  const float* wrow = Wenc + i * DV + vb;
  float4 w0 = *reinterpret_cast<const float4*>(wrow);
  float4 w1 = *reinterpret_cast<const float4*>(wrow + 4);
  float4 w2 = *reinterpret_cast<const float4*>(wrow + 8);
  float4 w3 = *reinterpret_cast<const float4*>(wrow + 12);
  bf16x8 o0, o1;
  o0[0] = (bf16)(vk * w0.x); o0[1] = (bf16)(vk * w0.y);
  o0[2] = (bf16)(vk * w0.z); o0[3] = (bf16)(vk * w0.w);
  o0[4] = (bf16)(vk * w1.x); o0[5] = (bf16)(vk * w1.y);
  o0[6] = (bf16)(vk * w1.z); o0[7] = (bf16)(vk * w1.w);
  o1[0] = (bf16)(vk * w2.x); o1[1] = (bf16)(vk * w2.y);
  o1[2] = (bf16)(vk * w2.z); o1[3] = (bf16)(vk * w2.w);
  o1[4] = (bf16)(vk * w3.x); o1[5] = (bf16)(vk * w3.y);
  o1[6] = (bf16)(vk * w3.z); o1[7] = (bf16)(vk * w3.w);
  bf16* out = Menc + (size_t)i * DD + (t << 4);
  *reinterpret_cast<bf16x8*>(out) = o0;
  *reinterpret_cast<bf16x8*>(out + 8) = o1;
}

// ---------------- GEMM: pre[1024,32768] = xb @ Menc^T + b_enc ----------------
#define BM 128
#define BN 128
#define BK 64

__global__ void k_gemm(const bf16* __restrict__ A, const bf16* __restrict__ Bt,
                       const float* __restrict__ benc, float* __restrict__ C) {
  __shared__ bf16 As[BM * BK];
  __shared__ bf16 Bs[BN * BK];
  int p = blockIdx.x;            // 0..7  (batch row-blocks, fast-varying for L2 panel reuse)
  int q = blockIdx.y;            // 0..255 (feature col-blocks)
  int brow = p * BM;
  int bcol = q * BN;
  int tid = threadIdx.x;
  int wave = tid >> 6;
  int lane = tid & 63;
  int wr = wave >> 1, wc = wave & 1;   // 2x2 wave grid, each wave 64x64

  f32x4 acc[4][4] = {};

  for (int k0 = 0; k0 < DD; k0 += BK) {
    // stage A/B tiles: chunk c = 1KB = 8 rows of 64 bf16; lane l -> row l>>3, col (l&7)*8
#pragma unroll
    for (int j = 0; j < 4; ++j) {
      int c = wave * 4 + j;
      int row = c * 8 + (lane >> 3);
      int col = (lane & 7) * 8;
      const bf16* ga = A + (size_t)(brow + row) * DD + k0 + col;
      const bf16* gb = Bt + (size_t)(bcol + row) * DD + k0 + col;
      gload_lds16(ga, As + c * 512);
      gload_lds16(gb, Bs + c * 512);
    }
    __syncthreads();

    const bf16* pa = As + (wr * 64 + (lane & 15)) * BK + (lane >> 4) * 8;
    const bf16* pb = Bs + (wc * 64 + (lane & 15)) * BK + (lane >> 4) * 8;
#pragma unroll
    for (int ks = 0; ks < 2; ++ks) {
      bf16x8 a[4], bb[4];
#pragma unroll
      for (int m = 0; m < 4; ++m)
        a[m] = *reinterpret_cast<const bf16x8*>(pa + m * 16 * BK + ks * 32);
#pragma unroll
      for (int n = 0; n < 4; ++n)
        bb[n] = *reinterpret_cast<const bf16x8*>(pb + n * 16 * BK + ks * 32);
#pragma unroll
      for (int m = 0; m < 4; ++m)
#pragma unroll
        for (int n = 0; n < 4; ++n)
          acc[m][n] = __builtin_amdgcn_mfma_f32_16x16x32_bf16(a[m], bb[n], acc[m][n], 0, 0, 0);
    }
    __syncthreads();
  }

  // epilogue: C/D layout col = lane&15, row = (lane>>4)*4 + r
#pragma unroll
  for (int n = 0; n < 4; ++n) {
    int col = bcol + wc * 64 + n * 16 + (lane & 15);
    float be = benc[col];
#pragma unroll
    for (int m = 0; m < 4; ++m) {
      int row0 = brow + wr * 64 + m * 16 + ((lane >> 4) << 2);
#pragma unroll
      for (int r = 0; r < 4; ++r)
        C[(size_t)(row0 + r) * NFEAT + col] = acc[m][n][r] + be;
    }
  }
}

// ---------------- per-row candidate extraction (top ~CAND_TARGET by bin) ----------------
__global__ void k_topk(const float* __restrict__ pre, int* __restrict__ cand_idx,
                       int* __restrict__ cand_cnt) {
  __shared__ int hist[8192];   // 13-bit bins of monotonic uint
  __shared__ int csum[256];
  __shared__ int sBstar;
  __shared__ int scount;
  int b = blockIdx.x;
  int t = threadIdx.x;
  const float* row = pre + (size_t)b * NFEAT;
  for (int i = t; i < 8192; i += 256) hist[i] = 0;
  if (t == 0) scount = 0;
  __syncthreads();

  for (int i = (t << 2); i < NFEAT; i += 1024) {
    float4 v = *reinterpret_cast<const float4*>(row + i);
    atomicAdd(&hist[monou(v.x) >> 19], 1);
    atomicAdd(&hist[monou(v.y) >> 19], 1);
    atomicAdd(&hist[monou(v.z) >> 19], 1);
    atomicAdd(&hist[monou(v.w) >> 19], 1);
  }
  __syncthreads();

  int s = 0;
  for (int i = 0; i < 32; ++i) s += hist[t * 32 + i];
  csum[t] = s;
  __syncthreads();
  int suff = 0;
  for (int j = t + 1; j < 256; ++j) suff += csum[j];
  if (suff < CAND_TARGET && suff + s >= CAND_TARGET) {
    int acc = suff;
    int bstar = t * 32;
    for (int i = 31; i >= 0; --i) {
      acc += hist[t * 32 + i];
      if (acc >= CAND_TARGET) { bstar = t * 32 + i; break; }
    }
    sBstar = bstar;
  }
  __syncthreads();
  int Bstar = sBstar;
  int* cidx = cand_idx + b * CAND_CAP;

  for (int i = (t << 2); i < NFEAT; i += 1024) {
    float4 v = *reinterpret_cast<const float4*>(row + i);
    unsigned b0 = monou(v.x) >> 19, b1 = monou(v.y) >> 19;
    unsigned b2 = monou(v.z) >> 19, b3 = monou(v.w) >> 19;
    if ((int)b0 >= Bstar) { int p2 = atomicAdd(&scount, 1); if (p2 < CAND_CAP) cidx[p2] = i; }
    if ((int)b1 >= Bstar) { int p2 = atomicAdd(&scount, 1); if (p2 < CAND_CAP) cidx[p2] = i + 1; }
    if ((int)b2 >= Bstar) { int p2 = atomicAdd(&scount, 1); if (p2 < CAND_CAP) cidx[p2] = i + 2; }
    if ((int)b3 >= Bstar) { int p2 = atomicAdd(&scount, 1); if (p2 < CAND_CAP) cidx[p2] = i + 3; }
  }
  __syncthreads();
  if (t == 0) cand_cnt[b] = (scount < CAND_CAP) ? scount : CAND_CAP;
}

// ---------------- fp32 refine + exact top-32 + scatter + decode + mse partial ----------------
__global__ void k_refine(const float* __restrict__ x,
                         const float* __restrict__ Venc,
                         const float* __restrict__ Wenc,
                         const float* __restrict__ benc,
                         const float* __restrict__ Vdec,
                         const float* __restrict__ Wdec,
                         const float* __restrict__ bias,
                         const int* __restrict__ cand_idx,
                         const int* __restrict__ cand_cnt,
                         float* __restrict__ recon,
                         float* __restrict__ coeffs,
                         float* __restrict__ msepart) {
  __shared__ float xl[DD];
  __shared__ float rval[CAND_CAP];
  __shared__ int ridx[CAND_CAP];
  __shared__ float selv[KSEL];
  __shared__ int seli[KSEL];
  __shared__ float Vd[KSEL][DK];
  __shared__ float Wd[KSEL][DV];
  __shared__ float red[256];

  int b = blockIdx.x;
  int t = threadIdx.x;
  int wave = t >> 6;
  int lane = t & 63;

  const float* xr = x + (size_t)b * DD;
  for (int i = (t << 2); i < DD; i += 1024)
    *reinterpret_cast<float4*>(xl + i) = *reinterpret_cast<const float4*>(xr + i);

  int c = cand_cnt[b];
  if (c > CAND_CAP) c = CAND_CAP;
  for (int i = t; i < c; i += 256) ridx[i] = cand_idx[b * CAND_CAP + i];
  __syncthreads();

  // exact fp32 pre for each candidate: lane = v, reduce over k then over v
  for (int j = wave; j < c; j += 4) {
    int fi = ridx[j];
    const float* vr = Venc + (size_t)fi * DK;
    float acc = 0.f;
#pragma unroll
    for (int kk = 0; kk < DK; kk += 4) {
      float4 v4 = *reinterpret_cast<const float4*>(vr + kk);
      acc = fmaf(xl[(kk + 0) * DV + lane], v4.x, acc);
      acc = fmaf(xl[(kk + 1) * DV + lane], v4.y, acc);
      acc = fmaf(xl[(kk + 2) * DV + lane], v4.z, acc);
      acc = fmaf(xl[(kk + 3) * DV + lane], v4.w, acc);
    }
    float p = acc * Wenc[(size_t)fi * DV + lane];
#pragma unroll
    for (int off = 1; off < 64; off <<= 1) p += __shfl_xor(p, off);
    if (lane == 0) rval[j] = p + benc[fi];
  }
  __syncthreads();

  // exact rank among candidates (tie-break: lower feature index wins, matches np)
  for (int t2 = t; t2 < c; t2 += 256) {
    float v = rval[t2];
    int fi = ridx[t2];
    int rank = 0;
    for (int j = 0; j < c; ++j) {
      float vj = rval[j];
      if (vj > v || (vj == v && ridx[j] < fi)) ++rank;
    }
    if (rank < KSEL) { selv[rank] = v; seli[rank] = fi; }
  }
  __syncthreads();

  if (t < KSEL) {
    float v = fmaxf(selv[t], 0.f);
    selv[t] = v;
    coeffs[(size_t)b * NFEAT + seli[t]] = v;
  }
  __syncthreads();

  for (int i = t; i < KSEL * DK; i += 256) {
    int s = i >> 6, e = i & 63;
    Vd[s][e] = Vdec[(size_t)seli[s] * DK + e];
    Wd[s][e] = Wdec[(size_t)seli[s] * DV + e];
  }
  __syncthreads();

  // decode: each thread owns 16 contiguous recon elements
  int k = t >> 2;
  int vb = (t & 3) << 4;
  float r[16];
  const float* bi = bias + k * DV + vb;
#pragma unroll
  for (int jj = 0; jj < 16; ++jj) r[jj] = bi[jj];
#pragma unroll
  for (int s = 0; s < KSEL; ++s) {
    float a = selv[s] * Vd[s][k];
#pragma unroll
    for (int jj = 0; jj < 16; ++jj) r[jj] = fmaf(a, Wd[s][vb + jj], r[jj]);
  }
  float m = 0.f;
  float* ro = recon + (size_t)b * DD + k * DV + vb;
#pragma unroll
  for (int jj = 0; jj < 16; ++jj) {
    float d = r[jj] - xl[k * DV + vb + jj];
    m = fmaf(d, d, m);
    ro[jj] = r[jj];
  }
  red[t] = m;
  __syncthreads();
  for (int s2 = 128; s2 > 0; s2 >>= 1) {
    if (t < s2) red[t] += red[t + s2];
    __syncthreads();
  }
  if (t == 0) msepart[b] = red[0];
}

__global__ void k_mse(const float* __restrict__ msepart, float* __restrict__ out) {
  __shared__ float red[256];
  int t = threadIdx.x;
  float s = 0.f;
  for (int i = t; i < BATCH; i += 256) s += msepart[i];
  red[t] = s;
  __syncthreads();
  for (int k = 128; k > 0; k >>= 1) {
    if (t < k) red[t] += red[t + k];
    __syncthreads();
  }
  if (t == 0) out[0] = red[0] / (float)((size_t)BATCH * DD);
}

extern "C" void kernel_launch(void* const* d_in, const int* in_sizes, int n_in,
                              void* d_out, int out_size, void* d_ws, size_t ws_size,
                              hipStream_t stream) {
  const float* x    = (const float*)d_in[0];
  const float* Venc = (const float*)d_in[1];
  const float* Wenc = (const float*)d_in[2];
  const float* benc = (const float*)d_in[3];
  const float* Vdec = (const float*)d_in[4];
  const float* Wdec = (const float*)d_in[5];
  const float* bias = (const float*)d_in[6];

  float* out = (float*)d_out;
  float* recon  = out;                                   // [1024, 4096]
  float* coeffs = out + (size_t)BATCH * DD;              // [1024, 32768]
  float* mse    = coeffs + (size_t)BATCH * NFEAT;        // [1]

  char* wsp = (char*)d_ws;
  bf16* xb = (bf16*)wsp;                 wsp += (size_t)BATCH * DD * sizeof(bf16);
  bf16* Menc = (bf16*)wsp;               wsp += (size_t)NFEAT * DD * sizeof(bf16);
  int* cand_idx = (int*)wsp;             wsp += (size_t)BATCH * CAND_CAP * sizeof(int);
  int* cand_cnt = (int*)wsp;             wsp += (size_t)BATCH * sizeof(int);
  float* msepart = (float*)wsp;          wsp += (size_t)BATCH * sizeof(float);

  float* pre = coeffs;  // reuse coeffs region as pre scratch (fully rewritten below)

  k_convert_x<<<(BATCH * DD) / (256 * 8), 256, 0, stream>>>(x, xb, BATCH * DD);
  k_build_menc<<<NFEAT, 256, 0, stream>>>(Venc, Wenc, Menc);
  dim3 g(BATCH / BM, NFEAT / BN);
  k_gemm<<<g, 256, 0, stream>>>(xb, Menc, benc, pre);
  k_topk<<<BATCH, 256, 0, stream>>>(pre, cand_idx, cand_cnt);
  hipMemsetAsync(coeffs, 0, ((size_t)BATCH * NFEAT + 1) * sizeof(float), stream);
  k_refine<<<BATCH, 256, 0, stream>>>(x, Venc, Wenc, benc, Vdec, Wdec, bias,
                                      cand_idx, cand_cnt, recon, coeffs, msepart);
  k_mse<<<1, 256, 0, stream>>>(msepart, mse);
}

// Round 2
// 534.455 us; speedup vs baseline: 1.0898x; 1.0898x over previous
//
#include <hip/hip_runtime.h>
#include <hip/hip_bf16.h>
#include <stdint.h>

#define NFEAT 32768
#define BATCH 1024
#define DK 64
#define DV 64
#define DD 4096
#define KSEL 32
#define CAND_CAP 512
#define CAND_TARGET 48

using bf16 = __bf16;
using bf16x8 = __attribute__((ext_vector_type(8))) __bf16;
using f32x4 = __attribute__((ext_vector_type(4))) float;

__device__ __forceinline__ void gload_lds16(const void* g, void* l) {
  __builtin_amdgcn_global_load_lds((const __attribute__((address_space(1))) void*)g,
                                   (__attribute__((address_space(3))) void*)l,
                                   16, 0, 0);
}

__device__ inline unsigned monou(float f) {
  unsigned u = __float_as_uint(f);
  return ((int)u < 0) ? ~u : (u | 0x80000000u);
}

// ---------------- x -> bf16 ----------------
__global__ void k_convert_x(const float* __restrict__ x, bf16* __restrict__ xb, int n) {
  int i = (blockIdx.x * blockDim.x + threadIdx.x) * 8;
  if (i >= n) return;
  float4 v0 = *reinterpret_cast<const float4*>(x + i);
  float4 v1 = *reinterpret_cast<const float4*>(x + i + 4);
  bf16x8 o;
  o[0] = (bf16)v0.x; o[1] = (bf16)v0.y; o[2] = (bf16)v0.z; o[3] = (bf16)v0.w;
  o[4] = (bf16)v1.x; o[5] = (bf16)v1.y; o[6] = (bf16)v1.z; o[7] = (bf16)v1.w;
  *reinterpret_cast<bf16x8*>(xb + i) = o;
}

// ---------------- M_enc[i][k*64+v] = V_enc[i][k] * W_enc[i][v] (bf16) ----------------
__global__ void k_build_menc(const float* __restrict__ Venc, const float* __restrict__ Wenc,
                             bf16* __restrict__ Menc) {
  int i = blockIdx.x;
  int t = threadIdx.x;
  int k = t >> 2;
  int vb = (t & 3) << 4;
  float vk = Venc[i * DK + k];
  const float* wrow = Wenc + i * DV + vb;
  float4 w0 = *reinterpret_cast<const float4*>(wrow);
  float4 w1 = *reinterpret_cast<const float4*>(wrow + 4);
  float4 w2 = *reinterpret_cast<const float4*>(wrow + 8);
  float4 w3 = *reinterpret_cast<const float4*>(wrow + 12);
  bf16x8 o0, o1;
  o0[0] = (bf16)(vk * w0.x); o0[1] = (bf16)(vk * w0.y);
  o0[2] = (bf16)(vk * w0.z); o0[3] = (bf16)(vk * w0.w);
  o0[4] = (bf16)(vk * w1.x); o0[5] = (bf16)(vk * w1.y);
  o0[6] = (bf16)(vk * w1.z); o0[7] = (bf16)(vk * w1.w);
  o1[0] = (bf16)(vk * w2.x); o1[1] = (bf16)(vk * w2.y);
  o1[2] = (bf16)(vk * w2.z); o1[3] = (bf16)(vk * w2.w);
  o1[4] = (bf16)(vk * w3.x); o1[5] = (bf16)(vk * w3.y);
  o1[6] = (bf16)(vk * w3.z); o1[7] = (bf16)(vk * w3.w);
  bf16* out = Menc + (size_t)i * DD + (t << 4);
  *reinterpret_cast<bf16x8*>(out) = o0;
  *reinterpret_cast<bf16x8*>(out + 8) = o1;
}

// ---------------- GEMM: pre[1024,32768] = xb @ Menc^T + b_enc ----------------
// 256x128 tile, BK=64, 8 waves (4M x 2N), triple-buffered LDS, counted vmcnt(6),
// st_16x32 XOR swizzle (linear LDS dest + pre-swizzled global source).
#define BM 256
#define BN 128
#define BK 64
#define NT (DD / BK)          // 64 K-tiles
#define ABUF 32768            // 256*64*2
#define BBUF 16384            // 128*64*2
#define BUFSZ (ABUF + BBUF)   // 48 KiB per buffer
#define GEMM_LDS (3 * BUFSZ)  // 144 KiB

// chunk c covers LDS bytes [c*1024, c*1024+1024) = rows 8c..8c+7 of a [rows][64]bf16 tile.
// lane l writes 16B at +16*l; source col slot is XOR-preswizzled so that a
// swizzled ds_read (colbyte ^ ((row&7)<<4)) returns the logical data.
__device__ __forceinline__ void stage_chunk(const bf16* __restrict__ G, size_t rowbase,
                                            int k0, int c, int lane, char* dstbase) {
  const bf16* src = G + (rowbase + (size_t)(c * 8 + (lane >> 3))) * DD + k0 +
                    (((lane & 7) ^ (lane >> 3)) << 3);
  gload_lds16(src, dstbase + c * 1024);
}

__device__ __forceinline__ bf16x8 frag_ld(const char* base, int row, int colbyte) {
  return *reinterpret_cast<const bf16x8*>(base + row * 128 + (colbyte ^ ((row & 7) << 4)));
}

__global__ __launch_bounds__(512, 2)
void k_gemm(const bf16* __restrict__ A, const bf16* __restrict__ Bt,
            const float* __restrict__ benc, float* __restrict__ C) {
  extern __shared__ char lds[];
  int tid = threadIdx.x;
  int wave = tid >> 6;
  int lane = tid & 63;
  int wr = wave >> 1;          // 0..3, 64 rows each
  int wc = wave & 1;           // 0..1, 64 cols each

  // XCD-grouped bijective remap: XCD x owns logical blocks [x*128,(x+1)*128);
  // logical = colpanel*4 + rowblock so each col-panel's 4 row-blocks are co-resident.
  int d = blockIdx.x;                  // 0..1023
  int lw = (d & 7) * 128 + (d >> 3);
  int q = lw >> 2;                     // col panel 0..255
  int p = lw & 3;                      // row block 0..3
  size_t brow = (size_t)p * BM;
  size_t bcol = (size_t)q * BN;

  f32x4 acc[4][4] = {};

  char* bufA = lds;                    // tile u
  char* bufB = lds + BUFSZ;            // tile u+1
  char* bufC = lds + 2 * BUFSZ;        // staging target (tile u+2)

  // prologue: stage tiles 0 and 1 (6 loads/thread each)
#pragma unroll
  for (int t = 0; t < 2; ++t) {
    char* Ab = lds + t * BUFSZ;
    char* Bb = Ab + ABUF;
    int k0 = t * BK;
    stage_chunk(A, brow, k0, wave, lane, Ab);
    stage_chunk(A, brow, k0, wave + 8, lane, Ab);
    stage_chunk(A, brow, k0, wave + 16, lane, Ab);
    stage_chunk(A, brow, k0, wave + 24, lane, Ab);
    stage_chunk(Bt, bcol, k0, wave, lane, Bb);
    stage_chunk(Bt, bcol, k0, wave + 8, lane, Bb);
  }

#pragma unroll 1
  for (int u = 0; u < NT; ++u) {
    // tile u's 6 loads are everything older than the newest 6 (tile u+1's).
    if (u == NT - 1)
      asm volatile("s_waitcnt vmcnt(0)" ::: "memory");
    else
      asm volatile("s_waitcnt vmcnt(6)" ::: "memory");
    asm volatile("s_waitcnt lgkmcnt(0)\n\ts_barrier" ::: "memory");

    char* Ab = bufA;
    char* Bb = bufA + ABUF;
    bool pf = (u + 2 < NT);
    int k2 = (u + 2) * BK;

    // ---- phase A: stage half of tile u+2; all B frags + A frags m0,m1; 16 MFMA ----
    if (pf) {
      stage_chunk(A, brow, k2, wave, lane, bufC);
      stage_chunk(A, brow, k2, wave + 8, lane, bufC);
      stage_chunk(Bt, bcol, k2, wave, lane, bufC + ABUF);
    }
    bf16x8 bfr[4][2];
#pragma unroll
    for (int n = 0; n < 4; ++n)
#pragma unroll
      for (int ks = 0; ks < 2; ++ks)
        bfr[n][ks] = frag_ld(Bb, wc * 64 + n * 16 + (lane & 15),
                             ks * 64 + ((lane >> 4) << 4));
    {
      bf16x8 afr[2][2];
#pragma unroll
      for (int m = 0; m < 2; ++m)
#pragma unroll
        for (int ks = 0; ks < 2; ++ks)
          afr[m][ks] = frag_ld(Ab, wr * 64 + m * 16 + (lane & 15),
                               ks * 64 + ((lane >> 4) << 4));
      __builtin_amdgcn_s_setprio(1);
#pragma unroll
      for (int m = 0; m < 2; ++m)
#pragma unroll
        for (int n = 0; n < 4; ++n)
#pragma unroll
          for (int ks = 0; ks < 2; ++ks)
            acc[m][n] = __builtin_amdgcn_mfma_f32_16x16x32_bf16(afr[m][ks], bfr[n][ks],
                                                                acc[m][n], 0, 0, 0);
      __builtin_amdgcn_s_setprio(0);
    }

    // ---- phase B: stage other half; A frags m2,m3; 16 MFMA ----
    if (pf) {
      stage_chunk(A, brow, k2, wave + 16, lane, bufC);
      stage_chunk(A, brow, k2, wave + 24, lane, bufC);
      stage_chunk(Bt, bcol, k2, wave + 8, lane, bufC + ABUF);
    }
    {
      bf16x8 afr[2][2];
#pragma unroll
      for (int m = 0; m < 2; ++m)
#pragma unroll
        for (int ks = 0; ks < 2; ++ks)
          afr[m][ks] = frag_ld(Ab, wr * 64 + (m + 2) * 16 + (lane & 15),
                               ks * 64 + ((lane >> 4) << 4));
      __builtin_amdgcn_s_setprio(1);
#pragma unroll
      for (int m = 0; m < 2; ++m)
#pragma unroll
        for (int n = 0; n < 4; ++n)
#pragma unroll
          for (int ks = 0; ks < 2; ++ks)
            acc[m + 2][n] = __builtin_amdgcn_mfma_f32_16x16x32_bf16(afr[m][ks], bfr[n][ks],
                                                                    acc[m + 2][n], 0, 0, 0);
      __builtin_amdgcn_s_setprio(0);
    }

    // rotate buffers
    char* t0 = bufA; bufA = bufB; bufB = bufC; bufC = t0;
  }

  // epilogue: C/D layout col = lane&15, row = (lane>>4)*4 + r
#pragma unroll
  for (int n = 0; n < 4; ++n) {
    size_t col = bcol + wc * 64 + n * 16 + (lane & 15);
    float be = benc[col];
#pragma unroll
    for (int m = 0; m < 4; ++m) {
      size_t row0 = brow + wr * 64 + m * 16 + ((lane >> 4) << 2);
#pragma unroll
      for (int r = 0; r < 4; ++r)
        C[(row0 + r) * NFEAT + col] = acc[m][n][r] + be;
    }
  }
}

// ---------------- per-row candidate extraction (top ~CAND_TARGET by bin) ----------------
__global__ void k_topk(const float* __restrict__ pre, int* __restrict__ cand_idx,
                       int* __restrict__ cand_cnt) {
  __shared__ int hist[8192];
  __shared__ int csum[256];
  __shared__ int sBstar;
  __shared__ int scount;
  int b = blockIdx.x;
  int t = threadIdx.x;
  const float* row = pre + (size_t)b * NFEAT;
  for (int i = t; i < 8192; i += 256) hist[i] = 0;
  if (t == 0) scount = 0;
  __syncthreads();

  for (int i = (t << 2); i < NFEAT; i += 1024) {
    float4 v = *reinterpret_cast<const float4*>(row + i);
    atomicAdd(&hist[monou(v.x) >> 19], 1);
    atomicAdd(&hist[monou(v.y) >> 19], 1);
    atomicAdd(&hist[monou(v.z) >> 19], 1);
    atomicAdd(&hist[monou(v.w) >> 19], 1);
  }
  __syncthreads();

  int s = 0;
  for (int i = 0; i < 32; ++i) s += hist[t * 32 + i];
  csum[t] = s;
  __syncthreads();
  int suff = 0;
  for (int j = t + 1; j < 256; ++j) suff += csum[j];
  if (suff < CAND_TARGET && suff + s >= CAND_TARGET) {
    int acc = suff;
    int bstar = t * 32;
    for (int i = 31; i >= 0; --i) {
      acc += hist[t * 32 + i];
      if (acc >= CAND_TARGET) { bstar = t * 32 + i; break; }
    }
    sBstar = bstar;
  }
  __syncthreads();
  int Bstar = sBstar;
  int* cidx = cand_idx + b * CAND_CAP;

  for (int i = (t << 2); i < NFEAT; i += 1024) {
    float4 v = *reinterpret_cast<const float4*>(row + i);
    unsigned b0 = monou(v.x) >> 19, b1 = monou(v.y) >> 19;
    unsigned b2 = monou(v.z) >> 19, b3 = monou(v.w) >> 19;
    if ((int)b0 >= Bstar) { int p2 = atomicAdd(&scount, 1); if (p2 < CAND_CAP) cidx[p2] = i; }
    if ((int)b1 >= Bstar) { int p2 = atomicAdd(&scount, 1); if (p2 < CAND_CAP) cidx[p2] = i + 1; }
    if ((int)b2 >= Bstar) { int p2 = atomicAdd(&scount, 1); if (p2 < CAND_CAP) cidx[p2] = i + 2; }
    if ((int)b3 >= Bstar) { int p2 = atomicAdd(&scount, 1); if (p2 < CAND_CAP) cidx[p2] = i + 3; }
  }
  __syncthreads();
  if (t == 0) cand_cnt[b] = (scount < CAND_CAP) ? scount : CAND_CAP;
}

// ---------------- fp32 refine + exact top-32 + zero+scatter + decode + mse partial ----------------
__global__ void k_refine(const float* __restrict__ x,
                         const float* __restrict__ Venc,
                         const float* __restrict__ Wenc,
                         const float* __restrict__ benc,
                         const float* __restrict__ Vdec,
                         const float* __restrict__ Wdec,
                         const float* __restrict__ bias,
                         const int* __restrict__ cand_idx,
                         const int* __restrict__ cand_cnt,
                         float* __restrict__ recon,
                         float* __restrict__ coeffs,
                         float* __restrict__ msepart) {
  __shared__ float xl[DD];
  __shared__ float rval[CAND_CAP];
  __shared__ int ridx[CAND_CAP];
  __shared__ float selv[KSEL];
  __shared__ int seli[KSEL];
  __shared__ float Vd[KSEL][DK];
  __shared__ float Wd[KSEL][DV];
  __shared__ float red[256];

  int b = blockIdx.x;
  int t = threadIdx.x;
  int wave = t >> 6;
  int lane = t & 63;

  // zero this row of coeffs (pre is dead after k_topk; this replaces the big memset)
  float* crow = coeffs + (size_t)b * NFEAT;
  float4 z4 = {0.f, 0.f, 0.f, 0.f};
  for (int i = (t << 2); i < NFEAT; i += 1024)
    *reinterpret_cast<float4*>(crow + i) = z4;

  const float* xr = x + (size_t)b * DD;
  for (int i = (t << 2); i < DD; i += 1024)
    *reinterpret_cast<float4*>(xl + i) = *reinterpret_cast<const float4*>(xr + i);

  int c = cand_cnt[b];
  if (c > CAND_CAP) c = CAND_CAP;
  for (int i = t; i < c; i += 256) ridx[i] = cand_idx[b * CAND_CAP + i];
  __syncthreads();

  // exact fp32 pre for each candidate
  for (int j = wave; j < c; j += 4) {
    int fi = ridx[j];
    const float* vr = Venc + (size_t)fi * DK;
    float acc = 0.f;
#pragma unroll
    for (int kk = 0; kk < DK; kk += 4) {
      float4 v4 = *reinterpret_cast<const float4*>(vr + kk);
      acc = fmaf(xl[(kk + 0) * DV + lane], v4.x, acc);
      acc = fmaf(xl[(kk + 1) * DV + lane], v4.y, acc);
      acc = fmaf(xl[(kk + 2) * DV + lane], v4.z, acc);
      acc = fmaf(xl[(kk + 3) * DV + lane], v4.w, acc);
    }
    float p = acc * Wenc[(size_t)fi * DV + lane];
#pragma unroll
    for (int off = 1; off < 64; off <<= 1) p += __shfl_xor(p, off);
    if (lane == 0) rval[j] = p + benc[fi];
  }
  __syncthreads();

  // exact rank among candidates (tie-break: lower feature index first, matches np)
  for (int t2 = t; t2 < c; t2 += 256) {
    float v = rval[t2];
    int fi = ridx[t2];
    int rank = 0;
    for (int j = 0; j < c; ++j) {
      float vj = rval[j];
      if (vj > v || (vj == v && ridx[j] < fi)) ++rank;
    }
    if (rank < KSEL) { selv[rank] = v; seli[rank] = fi; }
  }
  __syncthreads();

  if (t < KSEL) {
    float v = fmaxf(selv[t], 0.f);
    selv[t] = v;
    crow[seli[t]] = v;
  }
  __syncthreads();

  for (int i = t; i < KSEL * DK; i += 256) {
    int s = i >> 6, e = i & 63;
    Vd[s][e] = Vdec[(size_t)seli[s] * DK + e];
    Wd[s][e] = Wdec[(size_t)seli[s] * DV + e];
  }
  __syncthreads();

  int k = t >> 2;
  int vb = (t & 3) << 4;
  float r[16];
  const float* bi = bias + k * DV + vb;
#pragma unroll
  for (int jj = 0; jj < 16; ++jj) r[jj] = bi[jj];
#pragma unroll
  for (int s = 0; s < KSEL; ++s) {
    float a = selv[s] * Vd[s][k];
#pragma unroll
    for (int jj = 0; jj < 16; ++jj) r[jj] = fmaf(a, Wd[s][vb + jj], r[jj]);
  }
  float m = 0.f;
  float* ro = recon + (size_t)b * DD + k * DV + vb;
#pragma unroll
  for (int jj = 0; jj < 16; ++jj) {
    float dd = r[jj] - xl[k * DV + vb + jj];
    m = fmaf(dd, dd, m);
    ro[jj] = r[jj];
  }
  red[t] = m;
  __syncthreads();
  for (int s2 = 128; s2 > 0; s2 >>= 1) {
    if (t < s2) red[t] += red[t + s2];
    __syncthreads();
  }
  if (t == 0) msepart[b] = red[0];
}

__global__ void k_mse(const float* __restrict__ msepart, float* __restrict__ out) {
  __shared__ float red[256];
  int t = threadIdx.x;
  float s = 0.f;
  for (int i = t; i < BATCH; i += 256) s += msepart[i];
  red[t] = s;
  __syncthreads();
  for (int k = 128; k > 0; k >>= 1) {
    if (t < k) red[t] += red[t + k];
    __syncthreads();
  }
  if (t == 0) out[0] = red[0] / (float)((size_t)BATCH * DD);
}

extern "C" void kernel_launch(void* const* d_in, const int* in_sizes, int n_in,
                              void* d_out, int out_size, void* d_ws, size_t ws_size,
                              hipStream_t stream) {
  const float* x    = (const float*)d_in[0];
  const float* Venc = (const float*)d_in[1];
  const float* Wenc = (const float*)d_in[2];
  const float* benc = (const float*)d_in[3];
  const float* Vdec = (const float*)d_in[4];
  const float* Wdec = (const float*)d_in[5];
  const float* bias = (const float*)d_in[6];

  float* out = (float*)d_out;
  float* recon  = out;                                   // [1024, 4096]
  float* coeffs = out + (size_t)BATCH * DD;              // [1024, 32768]
  float* mse    = coeffs + (size_t)BATCH * NFEAT;        // [1]

  char* wsp = (char*)d_ws;
  bf16* xb = (bf16*)wsp;                 wsp += (size_t)BATCH * DD * sizeof(bf16);
  bf16* Menc = (bf16*)wsp;               wsp += (size_t)NFEAT * DD * sizeof(bf16);
  int* cand_idx = (int*)wsp;             wsp += (size_t)BATCH * CAND_CAP * sizeof(int);
  int* cand_cnt = (int*)wsp;             wsp += (size_t)BATCH * sizeof(int);
  float* msepart = (float*)wsp;          wsp += (size_t)BATCH * sizeof(float);

  float* pre = coeffs;  // reuse coeffs region as pre scratch (zeroed later by k_refine)

  hipFuncSetAttribute((const void*)k_gemm, hipFuncAttributeMaxDynamicSharedMemorySize,
                      GEMM_LDS);

  k_convert_x<<<(BATCH * DD) / (256 * 8), 256, 0, stream>>>(x, xb, BATCH * DD);
  k_build_menc<<<NFEAT, 256, 0, stream>>>(Venc, Wenc, Menc);
  k_gemm<<<(BATCH / BM) * (NFEAT / BN), 512, GEMM_LDS, stream>>>(xb, Menc, benc, pre);
  k_topk<<<BATCH, 256, 0, stream>>>(pre, cand_idx, cand_cnt);
  k_refine<<<BATCH, 256, 0, stream>>>(x, Venc, Wenc, benc, Vdec, Wdec, bias,
                                      cand_idx, cand_cnt, recon, coeffs, msepart);
  k_mse<<<1, 256, 0, stream>>>(msepart, mse);
}

// Round 4
// 499.195 us; speedup vs baseline: 1.1668x; 1.0706x over previous
//
#include <hip/hip_runtime.h>
#include <hip/hip_bf16.h>
#include <stdint.h>

#define NFEAT 32768
#define BATCH 1024
#define DK 64
#define DV 64
#define DD 4096
#define KSEL 32
#define CAND_CAP 512
#define CAND_TARGET 48

using bf16 = __bf16;
using bf16x8 = __attribute__((ext_vector_type(8))) __bf16;
using f32x4 = __attribute__((ext_vector_type(4))) float;

__device__ __forceinline__ void gload_lds16(const void* g, void* l) {
  __builtin_amdgcn_global_load_lds((const __attribute__((address_space(1))) void*)g,
                                   (__attribute__((address_space(3))) void*)l,
                                   16, 0, 0);
}

__device__ inline unsigned monou(float f) {
  unsigned u = __float_as_uint(f);
  return ((int)u < 0) ? ~u : (u | 0x80000000u);
}

// ---------------- x -> bf16 ----------------
__global__ void k_convert_x(const float* __restrict__ x, bf16* __restrict__ xb, int n) {
  int i = (blockIdx.x * blockDim.x + threadIdx.x) * 8;
  if (i >= n) return;
  float4 v0 = *reinterpret_cast<const float4*>(x + i);
  float4 v1 = *reinterpret_cast<const float4*>(x + i + 4);
  bf16x8 o;
  o[0] = (bf16)v0.x; o[1] = (bf16)v0.y; o[2] = (bf16)v0.z; o[3] = (bf16)v0.w;
  o[4] = (bf16)v1.x; o[5] = (bf16)v1.y; o[6] = (bf16)v1.z; o[7] = (bf16)v1.w;
  *reinterpret_cast<bf16x8*>(xb + i) = o;
}

// ---------------- M_enc[i][k*64+v] = V_enc[i][k] * W_enc[i][v] (bf16) ----------------
__global__ void k_build_menc(const float* __restrict__ Venc, const float* __restrict__ Wenc,
                             bf16* __restrict__ Menc) {
  int i = blockIdx.x;
  int t = threadIdx.x;
  int k = t >> 2;
  int vb = (t & 3) << 4;
  float vk = Venc[i * DK + k];
  const float* wrow = Wenc + i * DV + vb;
  float4 w0 = *reinterpret_cast<const float4*>(wrow);
  float4 w1 = *reinterpret_cast<const float4*>(wrow + 4);
  float4 w2 = *reinterpret_cast<const float4*>(wrow + 8);
  float4 w3 = *reinterpret_cast<const float4*>(wrow + 12);
  bf16x8 o0, o1;
  o0[0] = (bf16)(vk * w0.x); o0[1] = (bf16)(vk * w0.y);
  o0[2] = (bf16)(vk * w0.z); o0[3] = (bf16)(vk * w0.w);
  o0[4] = (bf16)(vk * w1.x); o0[5] = (bf16)(vk * w1.y);
  o0[6] = (bf16)(vk * w1.z); o0[7] = (bf16)(vk * w1.w);
  o1[0] = (bf16)(vk * w2.x); o1[1] = (bf16)(vk * w2.y);
  o1[2] = (bf16)(vk * w2.z); o1[3] = (bf16)(vk * w2.w);
  o1[4] = (bf16)(vk * w3.x); o1[5] = (bf16)(vk * w3.y);
  o1[6] = (bf16)(vk * w3.z); o1[7] = (bf16)(vk * w3.w);
  bf16* out = Menc + (size_t)i * DD + (t << 4);
  *reinterpret_cast<bf16x8*>(out) = o0;
  *reinterpret_cast<bf16x8*>(out + 8) = o1;
}

// ---------------- GEMM: pre[1024,32768] = xb @ Menc^T + b_enc ----------------
// 256x256 tile, BK=64, 8 waves (2M x 4N, per-wave C=128x64), double-buffered LDS,
// 4 phases/K-tile. Phase order: vmcnt(N) -> s_barrier -> stage-issue -> ds_read
// -> lgkmcnt(0) -> MFMA x16.  (vmcnt BEFORE barrier = cross-wave publication.)
#define BM 256
#define BN 256
#define BK 64
#define NT (DD / BK)          // 64 K-tiles
#define ABUF 32768            // 256*64*2
#define BUFSZ 65536           // A + B per K-tile
#define GEMM_LDS (2 * BUFSZ)  // 128 KiB

// chunk c = rows 8c..8c+7 of a [256][64]bf16 tile (1 KiB). lane l writes 16B at
// +16*l; source col slot XOR-preswizzled so swizzled ds_read returns logical data.
__device__ __forceinline__ void stage_chunk(const bf16* __restrict__ G, size_t rowbase,
                                            int k0, int c, int lane, char* dstbase) {
  const bf16* src = G + (rowbase + (size_t)(c * 8 + (lane >> 3))) * DD + k0 +
                    (((lane & 7) ^ (lane >> 3)) << 3);
  gload_lds16(src, dstbase + c * 1024);
}

__device__ __forceinline__ bf16x8 frag_ld(const char* base, int row, int colbyte) {
  return *reinterpret_cast<const bf16x8*>(base + row * 128 + (colbyte ^ ((row & 7) << 4)));
}

// half-tile chunk maps (idx = wave*2 + j, 0..15)
__device__ __forceinline__ int chA(int half, int idx) {
  return (idx < 8 ? idx : idx + 8) + half * 8;     // A0: rows 0-63 & 128-191
}
__device__ __forceinline__ int chB(int half, int idx) {
  return (idx >> 2) * 8 + (idx & 3) + half * 4;    // B0: first 32 rows of each 64-row band
}

#define LD_A(HALF)                                                                  \
  _Pragma("unroll") for (int m = 0; m < 4; ++m)                                     \
  _Pragma("unroll") for (int ks = 0; ks < 2; ++ks)                                  \
    afr[m][ks] = frag_ld(cur, wr * 128 + (HALF) * 64 + m * 16 + (lane & 15),        \
                         ks * 64 + ((lane >> 4) << 4));

#define LD_B(HALF)                                                                  \
  _Pragma("unroll") for (int n = 0; n < 2; ++n)                                     \
  _Pragma("unroll") for (int ks = 0; ks < 2; ++ks)                                  \
    bfr[n][ks] = frag_ld(cur + ABUF, wc * 64 + (HALF) * 32 + n * 16 + (lane & 15),  \
                         ks * 64 + ((lane >> 4) << 4));

#define ST_A(HALF, KT)                                                              \
  stage_chunk(A, brow, (KT) * BK, chA(HALF, wave * 2), lane, nxt);                  \
  stage_chunk(A, brow, (KT) * BK, chA(HALF, wave * 2 + 1), lane, nxt);

#define ST_B(HALF, KT)                                                              \
  stage_chunk(Bt, bcol, (KT) * BK, chB(HALF, wave * 2), lane, nxt + ABUF);          \
  stage_chunk(Bt, bcol, (KT) * BK, chB(HALF, wave * 2 + 1), lane, nxt + ABUF);

#define MFMA_Q(MBASE, NBASE)                                                        \
  asm volatile("s_waitcnt lgkmcnt(0)" ::: "memory");                                \
  __builtin_amdgcn_sched_barrier(0);                                                \
  __builtin_amdgcn_s_setprio(1);                                                    \
  _Pragma("unroll") for (int m = 0; m < 4; ++m)                                     \
  _Pragma("unroll") for (int n = 0; n < 2; ++n)                                     \
  _Pragma("unroll") for (int ks = 0; ks < 2; ++ks)                                  \
    acc[(MBASE) + m][(NBASE) + n] = __builtin_amdgcn_mfma_f32_16x16x32_bf16(        \
        afr[m][ks], bfr[n][ks], acc[(MBASE) + m][(NBASE) + n], 0, 0, 0);            \
  __builtin_amdgcn_s_setprio(0);

#define VMC(N) asm volatile("s_waitcnt vmcnt(" #N ")" ::: "memory");
#define BARR                                                                        \
  asm volatile("s_barrier" ::: "memory");                                           \
  __builtin_amdgcn_sched_barrier(0);

__global__ __launch_bounds__(512, 2)
void k_gemm(const bf16* __restrict__ A, const bf16* __restrict__ Bt,
            const float* __restrict__ benc, float* __restrict__ C) {
  extern __shared__ char lds[];
  int tid = threadIdx.x;
  int wave = tid >> 6;
  int lane = tid & 63;
  int wr = wave >> 2;          // 0..1, 128 rows each
  int wc = wave & 3;           // 0..3, 64 cols each

  // XCD-grouped bijective remap (512 blocks, 512%8==0)
  int d = blockIdx.x;                  // 0..511
  int lw = (d & 7) * 64 + (d >> 3);
  int q = lw >> 2;                     // col panel 0..127
  int p = lw & 3;                      // row block 0..3
  size_t brow = (size_t)p * BM;
  size_t bcol = (size_t)q * BN;

  f32x4 acc[8][4] = {};
  bf16x8 afr[4][2];
  bf16x8 bfr[2][2];

  // prologue: stage tile 0 into buf0, order B0,A0,B1,A1 (8 loads/thread)
  {
    char* nxt = lds;
    ST_B(0, 0) ST_A(0, 0) ST_B(1, 0) ST_A(1, 0)
  }

#pragma unroll 1
  for (int u = 0; u < NT - 1; ++u) {
    char* cur = lds + (u & 1) * BUFSZ;
    char* nxt = lds + ((u + 1) & 1) * BUFSZ;
    int k1 = u + 1;
    // q0: publish S(u,0),S(u,1); quadrant (A0,B0); stage B0(u+1)
    VMC(4)
    BARR
    ST_B(0, k1)
    LD_A(0) LD_B(0)
    MFMA_Q(0, 0)
    // q1: publish S(u,2)[,S(u,3)]; quadrant (A0,B1); stage A0(u+1)
    VMC(4)
    BARR
    ST_A(0, k1)
    LD_B(1)
    MFMA_Q(0, 2)
    // q2: quadrant (A1,B0); stage B1(u+1)
    VMC(4)
    BARR
    ST_B(1, k1)
    LD_A(1) LD_B(0)
    MFMA_Q(4, 0)
    // q3: quadrant (A1,B1); stage A1(u+1)
    BARR
    ST_A(1, k1)
    LD_B(1)
    MFMA_Q(4, 2)
  }

  // tail tile NT-1 (no staging)
  {
    char* cur = lds + ((NT - 1) & 1) * BUFSZ;
    VMC(4)
    BARR
    LD_A(0) LD_B(0)
    MFMA_Q(0, 0)
    VMC(2)
    BARR
    LD_B(1)
    MFMA_Q(0, 2)
    VMC(0)
    BARR
    LD_A(1) LD_B(0)
    MFMA_Q(4, 0)
    BARR
    LD_B(1)
    MFMA_Q(4, 2)
  }

  // epilogue: C/D layout col = lane&15, row = (lane>>4)*4 + r
#pragma unroll
  for (int nf = 0; nf < 4; ++nf) {
    size_t col = bcol + wc * 64 + nf * 16 + (lane & 15);
    float be = benc[col];
#pragma unroll
    for (int mf = 0; mf < 8; ++mf) {
      size_t row0 = brow + wr * 128 + mf * 16 + ((lane >> 4) << 2);
#pragma unroll
      for (int r = 0; r < 4; ++r)
        C[(row0 + r) * NFEAT + col] = acc[mf][nf][r] + be;
    }
  }
}

// ---------------- per-row candidate extraction (top ~CAND_TARGET by bin) ----------------
__global__ void k_topk(const float* __restrict__ pre, int* __restrict__ cand_idx,
                       int* __restrict__ cand_cnt) {
  __shared__ int hist[8192];
  __shared__ int csum[256];
  __shared__ int sBstar;
  __shared__ int scount;
  int b = blockIdx.x;
  int t = threadIdx.x;
  const float* row = pre + (size_t)b * NFEAT;
  for (int i = t; i < 8192; i += 256) hist[i] = 0;
  if (t == 0) scount = 0;
  __syncthreads();

  for (int i = (t << 2); i < NFEAT; i += 1024) {
    float4 v = *reinterpret_cast<const float4*>(row + i);
    atomicAdd(&hist[monou(v.x) >> 19], 1);
    atomicAdd(&hist[monou(v.y) >> 19], 1);
    atomicAdd(&hist[monou(v.z) >> 19], 1);
    atomicAdd(&hist[monou(v.w) >> 19], 1);
  }
  __syncthreads();

  int s = 0;
  for (int i = 0; i < 32; ++i) s += hist[t * 32 + i];
  csum[t] = s;
  __syncthreads();
  int suff = 0;
  for (int j = t + 1; j < 256; ++j) suff += csum[j];
  if (suff < CAND_TARGET && suff + s >= CAND_TARGET) {
    int acc = suff;
    int bstar = t * 32;
    for (int i = 31; i >= 0; --i) {
      acc += hist[t * 32 + i];
      if (acc >= CAND_TARGET) { bstar = t * 32 + i; break; }
    }
    sBstar = bstar;
  }
  __syncthreads();
  int Bstar = sBstar;
  int* cidx = cand_idx + b * CAND_CAP;

  for (int i = (t << 2); i < NFEAT; i += 1024) {
    float4 v = *reinterpret_cast<const float4*>(row + i);
    unsigned b0 = monou(v.x) >> 19, b1 = monou(v.y) >> 19;
    unsigned b2 = monou(v.z) >> 19, b3 = monou(v.w) >> 19;
    if ((int)b0 >= Bstar) { int p2 = atomicAdd(&scount, 1); if (p2 < CAND_CAP) cidx[p2] = i; }
    if ((int)b1 >= Bstar) { int p2 = atomicAdd(&scount, 1); if (p2 < CAND_CAP) cidx[p2] = i + 1; }
    if ((int)b2 >= Bstar) { int p2 = atomicAdd(&scount, 1); if (p2 < CAND_CAP) cidx[p2] = i + 2; }
    if ((int)b3 >= Bstar) { int p2 = atomicAdd(&scount, 1); if (p2 < CAND_CAP) cidx[p2] = i + 3; }
  }
  __syncthreads();
  if (t == 0) cand_cnt[b] = (scount < CAND_CAP) ? scount : CAND_CAP;
}

// ---------------- fp32 refine + exact top-32 + zero+scatter + decode + mse partial ----------------
__global__ void k_refine(const float* __restrict__ x,
                         const float* __restrict__ Venc,
                         const float* __restrict__ Wenc,
                         const float* __restrict__ benc,
                         const float* __restrict__ Vdec,
                         const float* __restrict__ Wdec,
                         const float* __restrict__ bias,
                         const int* __restrict__ cand_idx,
                         const int* __restrict__ cand_cnt,
                         float* __restrict__ recon,
                         float* __restrict__ coeffs,
                         float* __restrict__ msepart) {
  __shared__ float xl[DD];
  __shared__ float rval[CAND_CAP];
  __shared__ int ridx[CAND_CAP];
  __shared__ float selv[KSEL];
  __shared__ int seli[KSEL];
  __shared__ float Vd[KSEL][DK];
  __shared__ float Wd[KSEL][DV];
  __shared__ float red[256];

  int b = blockIdx.x;
  int t = threadIdx.x;
  int wave = t >> 6;
  int lane = t & 63;

  // zero this row of coeffs (pre is dead after k_topk)
  float* crow = coeffs + (size_t)b * NFEAT;
  float4 z4 = {0.f, 0.f, 0.f, 0.f};
  for (int i = (t << 2); i < NFEAT; i += 1024)
    *reinterpret_cast<float4*>(crow + i) = z4;

  const float* xr = x + (size_t)b * DD;
  for (int i = (t << 2); i < DD; i += 1024)
    *reinterpret_cast<float4*>(xl + i) = *reinterpret_cast<const float4*>(xr + i);

  int c = cand_cnt[b];
  if (c > CAND_CAP) c = CAND_CAP;
  for (int i = t; i < c; i += 256) ridx[i] = cand_idx[b * CAND_CAP + i];
  __syncthreads();

  // exact fp32 pre for each candidate
  for (int j = wave; j < c; j += 4) {
    int fi = ridx[j];
    const float* vr = Venc + (size_t)fi * DK;
    float acc = 0.f;
#pragma unroll
    for (int kk = 0; kk < DK; kk += 4) {
      float4 v4 = *reinterpret_cast<const float4*>(vr + kk);
      acc = fmaf(xl[(kk + 0) * DV + lane], v4.x, acc);
      acc = fmaf(xl[(kk + 1) * DV + lane], v4.y, acc);
      acc = fmaf(xl[(kk + 2) * DV + lane], v4.z, acc);
      acc = fmaf(xl[(kk + 3) * DV + lane], v4.w, acc);
    }
    float p2 = acc * Wenc[(size_t)fi * DV + lane];
#pragma unroll
    for (int off = 1; off < 64; off <<= 1) p2 += __shfl_xor(p2, off);
    if (lane == 0) rval[j] = p2 + benc[fi];
  }
  __syncthreads();

  // exact rank among candidates (tie-break: lower feature index first, matches np)
  for (int t2 = t; t2 < c; t2 += 256) {
    float v = rval[t2];
    int fi = ridx[t2];
    int rank = 0;
    for (int j = 0; j < c; ++j) {
      float vj = rval[j];
      if (vj > v || (vj == v && ridx[j] < fi)) ++rank;
    }
    if (rank < KSEL) { selv[rank] = v; seli[rank] = fi; }
  }
  __syncthreads();

  if (t < KSEL) {
    float v = fmaxf(selv[t], 0.f);
    selv[t] = v;
    crow[seli[t]] = v;
  }
  __syncthreads();

  for (int i = t; i < KSEL * DK; i += 256) {
    int s = i >> 6, e = i & 63;
    Vd[s][e] = Vdec[(size_t)seli[s] * DK + e];
    Wd[s][e] = Wdec[(size_t)seli[s] * DV + e];
  }
  __syncthreads();

  int k = t >> 2;
  int vb = (t & 3) << 4;
  float r[16];
  const float* bi = bias + k * DV + vb;
#pragma unroll
  for (int jj = 0; jj < 16; ++jj) r[jj] = bi[jj];
#pragma unroll
  for (int s = 0; s < KSEL; ++s) {
    float a = selv[s] * Vd[s][k];
#pragma unroll
    for (int jj = 0; jj < 16; ++jj) r[jj] = fmaf(a, Wd[s][vb + jj], r[jj]);
  }
  float m = 0.f;
  float* ro = recon + (size_t)b * DD + k * DV + vb;
#pragma unroll
  for (int jj = 0; jj < 16; ++jj) {
    float dd = r[jj] - xl[k * DV + vb + jj];
    m = fmaf(dd, dd, m);
    ro[jj] = r[jj];
  }
  red[t] = m;
  __syncthreads();
  for (int s2 = 128; s2 > 0; s2 >>= 1) {
    if (t < s2) red[t] += red[t + s2];
    __syncthreads();
  }
  if (t == 0) msepart[b] = red[0];
}

__global__ void k_mse(const float* __restrict__ msepart, float* __restrict__ out) {
  __shared__ float red[256];
  int t = threadIdx.x;
  float s = 0.f;
  for (int i = t; i < BATCH; i += 256) s += msepart[i];
  red[t] = s;
  __syncthreads();
  for (int k = 128; k > 0; k >>= 1) {
    if (t < k) red[t] += red[t + k];
    __syncthreads();
  }
  if (t == 0) out[0] = red[0] / (float)((size_t)BATCH * DD);
}

extern "C" void kernel_launch(void* const* d_in, const int* in_sizes, int n_in,
                              void* d_out, int out_size, void* d_ws, size_t ws_size,
                              hipStream_t stream) {
  const float* x    = (const float*)d_in[0];
  const float* Venc = (const float*)d_in[1];
  const float* Wenc = (const float*)d_in[2];
  const float* benc = (const float*)d_in[3];
  const float* Vdec = (const float*)d_in[4];
  const float* Wdec = (const float*)d_in[5];
  const float* bias = (const float*)d_in[6];

  float* out = (float*)d_out;
  float* recon  = out;                                   // [1024, 4096]
  float* coeffs = out + (size_t)BATCH * DD;              // [1024, 32768]
  float* mse    = coeffs + (size_t)BATCH * NFEAT;        // [1]

  char* wsp = (char*)d_ws;
  bf16* xb = (bf16*)wsp;                 wsp += (size_t)BATCH * DD * sizeof(bf16);
  bf16* Menc = (bf16*)wsp;               wsp += (size_t)NFEAT * DD * sizeof(bf16);
  int* cand_idx = (int*)wsp;             wsp += (size_t)BATCH * CAND_CAP * sizeof(int);
  int* cand_cnt = (int*)wsp;             wsp += (size_t)BATCH * sizeof(int);
  float* msepart = (float*)wsp;          wsp += (size_t)BATCH * sizeof(float);

  float* pre = coeffs;  // reuse coeffs region as pre scratch (zeroed later by k_refine)

  hipFuncSetAttribute((const void*)k_gemm, hipFuncAttributeMaxDynamicSharedMemorySize,
                      GEMM_LDS);

  k_convert_x<<<(BATCH * DD) / (256 * 8), 256, 0, stream>>>(x, xb, BATCH * DD);
  k_build_menc<<<NFEAT, 256, 0, stream>>>(Venc, Wenc, Menc);
  k_gemm<<<(BATCH / BM) * (NFEAT / BN), 512, GEMM_LDS, stream>>>(xb, Menc, benc, pre);
  k_topk<<<BATCH, 256, 0, stream>>>(pre, cand_idx, cand_cnt);
  k_refine<<<BATCH, 256, 0, stream>>>(x, Venc, Wenc, benc, Vdec, Wdec, bias,
                                      cand_idx, cand_cnt, recon, coeffs, msepart);
  k_mse<<<1, 256, 0, stream>>>(msepart, mse);
}

// Round 5
// 492.101 us; speedup vs baseline: 1.1836x; 1.0144x over previous
//
#include <hip/hip_runtime.h>
#include <hip/hip_bf16.h>
#include <stdint.h>

#define NFEAT 32768
#define BATCH 1024
#define DK 64
#define DV 64
#define DD 4096
#define KSEL 32
#define CAND_CAP 512
#define CAND_TARGET 64

using bf16 = __bf16;
using bf16x8 = __attribute__((ext_vector_type(8))) __bf16;
using f32x4 = __attribute__((ext_vector_type(4))) float;

__device__ __forceinline__ void gload_lds16(const void* g, void* l) {
  __builtin_amdgcn_global_load_lds((const __attribute__((address_space(1))) void*)g,
                                   (__attribute__((address_space(3))) void*)l,
                                   16, 0, 0);
}

__device__ inline unsigned mono16(unsigned u) {
  return (u & 0x8000u) ? ((~u) & 0xFFFFu) : (u | 0x8000u);
}

// ---------------- x -> bf16 ----------------
__global__ void k_convert_x(const float* __restrict__ x, bf16* __restrict__ xb, int n) {
  int i = (blockIdx.x * blockDim.x + threadIdx.x) * 8;
  if (i >= n) return;
  float4 v0 = *reinterpret_cast<const float4*>(x + i);
  float4 v1 = *reinterpret_cast<const float4*>(x + i + 4);
  bf16x8 o;
  o[0] = (bf16)v0.x; o[1] = (bf16)v0.y; o[2] = (bf16)v0.z; o[3] = (bf16)v0.w;
  o[4] = (bf16)v1.x; o[5] = (bf16)v1.y; o[6] = (bf16)v1.z; o[7] = (bf16)v1.w;
  *reinterpret_cast<bf16x8*>(xb + i) = o;
}

// ---------------- M_enc[i][k*64+v] = V_enc[i][k] * W_enc[i][v] (bf16) ----------------
__global__ void k_build_menc(const float* __restrict__ Venc, const float* __restrict__ Wenc,
                             bf16* __restrict__ Menc) {
  int i = blockIdx.x;
  int t = threadIdx.x;
  int k = t >> 2;
  int vb = (t & 3) << 4;
  float vk = Venc[i * DK + k];
  const float* wrow = Wenc + i * DV + vb;
  float4 w0 = *reinterpret_cast<const float4*>(wrow);
  float4 w1 = *reinterpret_cast<const float4*>(wrow + 4);
  float4 w2 = *reinterpret_cast<const float4*>(wrow + 8);
  float4 w3 = *reinterpret_cast<const float4*>(wrow + 12);
  bf16x8 o0, o1;
  o0[0] = (bf16)(vk * w0.x); o0[1] = (bf16)(vk * w0.y);
  o0[2] = (bf16)(vk * w0.z); o0[3] = (bf16)(vk * w0.w);
  o0[4] = (bf16)(vk * w1.x); o0[5] = (bf16)(vk * w1.y);
  o0[6] = (bf16)(vk * w1.z); o0[7] = (bf16)(vk * w1.w);
  o1[0] = (bf16)(vk * w2.x); o1[1] = (bf16)(vk * w2.y);
  o1[2] = (bf16)(vk * w2.z); o1[3] = (bf16)(vk * w2.w);
  o1[4] = (bf16)(vk * w3.x); o1[5] = (bf16)(vk * w3.y);
  o1[6] = (bf16)(vk * w3.z); o1[7] = (bf16)(vk * w3.w);
  bf16* out = Menc + (size_t)i * DD + (t << 4);
  *reinterpret_cast<bf16x8*>(out) = o0;
  *reinterpret_cast<bf16x8*>(out + 8) = o1;
}

// ---------------- GEMM: pre[1024,32768] = bf16(xb @ Menc^T + b_enc) ----------------
// 256x256, BK=64, 8 waves (2M x 4N), double-buffered LDS, 4 phases/K-tile.
// Phase: ds_read -> stage-issue -> vmcnt(N) -> s_barrier -> lgkmcnt(0) -> MFMA -> s_barrier.
// ds_read(p)'s data was vmcnt-published before an earlier barrier (see derivation).
#define BM 256
#define BN 256
#define BK 64
#define NT (DD / BK)          // 64 K-tiles
#define ABUF 32768            // 256*64*2
#define BUFSZ 65536           // A + B per K-tile
#define GEMM_LDS (2 * BUFSZ)  // 128 KiB

__device__ __forceinline__ void stage_chunk(const bf16* __restrict__ G, size_t rowbase,
                                            int k0, int c, int lane, char* dstbase) {
  const bf16* src = G + (rowbase + (size_t)(c * 8 + (lane >> 3))) * DD + k0 +
                    (((lane & 7) ^ (lane >> 3)) << 3);
  gload_lds16(src, dstbase + c * 1024);
}

__device__ __forceinline__ bf16x8 frag_ld(const char* base, int row, int colbyte) {
  return *reinterpret_cast<const bf16x8*>(base + row * 128 + (colbyte ^ ((row & 7) << 4)));
}

// half-tile chunk maps (idx = wave*2 + j, 0..15)
__device__ __forceinline__ int chA(int half, int idx) {
  return (idx < 8 ? idx : idx + 8) + half * 8;     // A0: rows 0-63 & 128-191
}
__device__ __forceinline__ int chB(int half, int idx) {
  return (idx >> 2) * 8 + (idx & 3) + half * 4;    // B0: first 32 rows of each 64-row band
}

#define LD_A(HALF)                                                                  \
  _Pragma("unroll") for (int m = 0; m < 4; ++m)                                     \
  _Pragma("unroll") for (int ks = 0; ks < 2; ++ks)                                  \
    afr[m][ks] = frag_ld(cur, wr * 128 + (HALF) * 64 + m * 16 + (lane & 15),        \
                         ks * 64 + ((lane >> 4) << 4));

#define LD_B(HALF)                                                                  \
  _Pragma("unroll") for (int n = 0; n < 2; ++n)                                     \
  _Pragma("unroll") for (int ks = 0; ks < 2; ++ks)                                  \
    bfr[n][ks] = frag_ld(cur + ABUF, wc * 64 + (HALF) * 32 + n * 16 + (lane & 15),  \
                         ks * 64 + ((lane >> 4) << 4));

#define ST_A(HALF, KT)                                                              \
  stage_chunk(A, brow, (KT) * BK, chA(HALF, wave * 2), lane, nxt);                  \
  stage_chunk(A, brow, (KT) * BK, chA(HALF, wave * 2 + 1), lane, nxt);

#define ST_B(HALF, KT)                                                              \
  stage_chunk(Bt, bcol, (KT) * BK, chB(HALF, wave * 2), lane, nxt + ABUF);          \
  stage_chunk(Bt, bcol, (KT) * BK, chB(HALF, wave * 2 + 1), lane, nxt + ABUF);

#define MFMA_Q(MBASE, NBASE)                                                        \
  asm volatile("s_waitcnt lgkmcnt(0)" ::: "memory");                                \
  __builtin_amdgcn_sched_barrier(0);                                                \
  __builtin_amdgcn_s_setprio(1);                                                    \
  _Pragma("unroll") for (int m = 0; m < 4; ++m)                                     \
  _Pragma("unroll") for (int n = 0; n < 2; ++n)                                     \
  _Pragma("unroll") for (int ks = 0; ks < 2; ++ks)                                  \
    acc[(MBASE) + m][(NBASE) + n] = __builtin_amdgcn_mfma_f32_16x16x32_bf16(        \
        afr[m][ks], bfr[n][ks], acc[(MBASE) + m][(NBASE) + n], 0, 0, 0);            \
  __builtin_amdgcn_s_setprio(0);

#define VMC(N) asm volatile("s_waitcnt vmcnt(" #N ")" ::: "memory");
#define BARR                                                                        \
  asm volatile("s_barrier" ::: "memory");                                           \
  __builtin_amdgcn_sched_barrier(0);

__global__ __launch_bounds__(512, 2)
void k_gemm(const bf16* __restrict__ A, const bf16* __restrict__ Bt,
            const float* __restrict__ benc, bf16* __restrict__ C) {
  extern __shared__ char lds[];
  int tid = threadIdx.x;
  int wave = tid >> 6;
  int lane = tid & 63;
  int wr = wave >> 2;          // 0..1, 128 rows each
  int wc = wave & 3;           // 0..3, 64 cols each

  // XCD-grouped bijective remap (512 blocks, 512%8==0)
  int d = blockIdx.x;                  // 0..511
  int lw = (d & 7) * 64 + (d >> 3);
  int q = lw >> 2;                     // col panel 0..127
  int p = lw & 3;                      // row block 0..3
  size_t brow = (size_t)p * BM;
  size_t bcol = (size_t)q * BN;

  f32x4 acc[8][4] = {};
  bf16x8 afr[4][2];
  bf16x8 bfr[2][2];

  // prologue: stage tile 0 into buf0 (order B0,A0,B1,A1); publish B0,A0; barrier.
  {
    char* nxt = lds;
    ST_B(0, 0) ST_A(0, 0) ST_B(1, 0) ST_A(1, 0)
  }
  VMC(4)
  BARR

#pragma unroll 1
  for (int u = 0; u < NT - 1; ++u) {
    char* cur = lds + (u & 1) * BUFSZ;
    char* nxt = lds + ((u + 1) & 1) * BUFSZ;
    int k1 = u + 1;
    // q0: read A0,B0(u); stage B0(u+1); vmcnt publishes B1(u) for q1
    LD_A(0) LD_B(0)
    ST_B(0, k1)
    VMC(4)
    BARR
    MFMA_Q(0, 0)
    BARR
    // q1: read B1(u); stage A0(u+1); vmcnt publishes A1(u) for q2
    LD_B(1)
    ST_A(0, k1)
    VMC(4)
    BARR
    MFMA_Q(0, 2)
    BARR
    // q2: read A1(u),B0(u); stage B1(u+1); no wait needed
    LD_A(1) LD_B(0)
    ST_B(1, k1)
    BARR
    MFMA_Q(4, 0)
    BARR
    // q3: read B1(u); stage A1(u+1); vmcnt publishes B0,A0(u+1) for q0(u+1)
    LD_B(1)
    ST_A(1, k1)
    VMC(4)
    BARR
    MFMA_Q(4, 2)
    BARR
  }

  // tail tile NT-1 (no staging); remaining outstanding on entry: B1,A1 of this tile (4)
  {
    char* cur = lds + ((NT - 1) & 1) * BUFSZ;
    LD_A(0) LD_B(0)
    VMC(2)
    BARR
    MFMA_Q(0, 0)
    BARR
    LD_B(1)
    VMC(0)
    BARR
    MFMA_Q(0, 2)
    BARR
    LD_A(1) LD_B(0)
    BARR
    MFMA_Q(4, 0)
    BARR
    LD_B(1)
    BARR
    MFMA_Q(4, 2)
  }

  // epilogue: C/D layout col = lane&15, row = (lane>>4)*4 + r; store bf16
#pragma unroll
  for (int nf = 0; nf < 4; ++nf) {
    size_t col = bcol + wc * 64 + nf * 16 + (lane & 15);
    float be = benc[col];
#pragma unroll
    for (int mf = 0; mf < 8; ++mf) {
      size_t row0 = brow + wr * 128 + mf * 16 + ((lane >> 4) << 2);
#pragma unroll
      for (int r = 0; r < 4; ++r)
        C[(row0 + r) * NFEAT + col] = (bf16)(acc[mf][nf][r] + be);
    }
  }
}

// ---------------- per-row candidate extraction from bf16 pre ----------------
__global__ void k_topk(const unsigned short* __restrict__ pre, int* __restrict__ cand_idx,
                       int* __restrict__ cand_cnt) {
  __shared__ int hist[8192];   // 13-bit bins of 16-bit monotonic code
  __shared__ int csum[256];
  __shared__ int sBstar;
  __shared__ int scount;
  int b = blockIdx.x;
  int t = threadIdx.x;
  const unsigned short* row = pre + (size_t)b * NFEAT;
  for (int i = t; i < 8192; i += 256) hist[i] = 0;
  if (t == 0) scount = 0;
  __syncthreads();

  for (int i = (t << 3); i < NFEAT; i += 2048) {
    uint4 v = *reinterpret_cast<const uint4*>(row + i);
#pragma unroll
    for (int j = 0; j < 4; ++j) {
      unsigned w = (&v.x)[j];
      atomicAdd(&hist[mono16(w & 0xFFFFu) >> 3], 1);
      atomicAdd(&hist[mono16(w >> 16) >> 3], 1);
    }
  }
  __syncthreads();

  int s = 0;
  for (int i = 0; i < 32; ++i) s += hist[t * 32 + i];
  csum[t] = s;
  __syncthreads();
  int suff = 0;
  for (int j = t + 1; j < 256; ++j) suff += csum[j];
  if (suff < CAND_TARGET && suff + s >= CAND_TARGET) {
    int acc = suff;
    int bstar = t * 32;
    for (int i = 31; i >= 0; --i) {
      acc += hist[t * 32 + i];
      if (acc >= CAND_TARGET) { bstar = t * 32 + i; break; }
    }
    sBstar = bstar;
  }
  __syncthreads();
  int Bstar = sBstar;
  int* cidx = cand_idx + b * CAND_CAP;

  for (int i = (t << 3); i < NFEAT; i += 2048) {
    uint4 v = *reinterpret_cast<const uint4*>(row + i);
#pragma unroll
    for (int j = 0; j < 4; ++j) {
      unsigned w = (&v.x)[j];
      int b0 = (int)(mono16(w & 0xFFFFu) >> 3);
      int b1 = (int)(mono16(w >> 16) >> 3);
      if (b0 >= Bstar) { int p2 = atomicAdd(&scount, 1); if (p2 < CAND_CAP) cidx[p2] = i + j * 2; }
      if (b1 >= Bstar) { int p2 = atomicAdd(&scount, 1); if (p2 < CAND_CAP) cidx[p2] = i + j * 2 + 1; }
    }
  }
  __syncthreads();
  if (t == 0) cand_cnt[b] = (scount < CAND_CAP) ? scount : CAND_CAP;
}

// ---------------- fp32 refine + exact top-32 + zero+scatter + decode + mse partial ----------------
__global__ void k_refine(const float* __restrict__ x,
                         const float* __restrict__ Venc,
                         const float* __restrict__ Wenc,
                         const float* __restrict__ benc,
                         const float* __restrict__ Vdec,
                         const float* __restrict__ Wdec,
                         const float* __restrict__ bias,
                         const int* __restrict__ cand_idx,
                         const int* __restrict__ cand_cnt,
                         float* __restrict__ recon,
                         float* __restrict__ coeffs,
                         float* __restrict__ msepart) {
  __shared__ float xl[DD];
  __shared__ float rval[CAND_CAP];
  __shared__ int ridx[CAND_CAP];
  __shared__ float selv[KSEL];
  __shared__ int seli[KSEL];
  __shared__ float Vd[KSEL][DK];
  __shared__ float Wd[KSEL][DV];
  __shared__ float red[256];

  int b = blockIdx.x;
  int t = threadIdx.x;
  int wave = t >> 6;
  int lane = t & 63;

  // zero this row of coeffs (pre is dead after k_topk)
  float* crow = coeffs + (size_t)b * NFEAT;
  float4 z4 = {0.f, 0.f, 0.f, 0.f};
  for (int i = (t << 2); i < NFEAT; i += 1024)
    *reinterpret_cast<float4*>(crow + i) = z4;

  const float* xr = x + (size_t)b * DD;
  for (int i = (t << 2); i < DD; i += 1024)
    *reinterpret_cast<float4*>(xl + i) = *reinterpret_cast<const float4*>(xr + i);

  int c = cand_cnt[b];
  if (c > CAND_CAP) c = CAND_CAP;
  for (int i = t; i < c; i += 256) ridx[i] = cand_idx[b * CAND_CAP + i];
  __syncthreads();

  // exact fp32 pre for each candidate
  for (int j = wave; j < c; j += 4) {
    int fi = ridx[j];
    const float* vr = Venc + (size_t)fi * DK;
    float acc = 0.f;
#pragma unroll
    for (int kk = 0; kk < DK; kk += 4) {
      float4 v4 = *reinterpret_cast<const float4*>(vr + kk);
      acc = fmaf(xl[(kk + 0) * DV + lane], v4.x, acc);
      acc = fmaf(xl[(kk + 1) * DV + lane], v4.y, acc);
      acc = fmaf(xl[(kk + 2) * DV + lane], v4.z, acc);
      acc = fmaf(xl[(kk + 3) * DV + lane], v4.w, acc);
    }
    float p2 = acc * Wenc[(size_t)fi * DV + lane];
#pragma unroll
    for (int off = 1; off < 64; off <<= 1) p2 += __shfl_xor(p2, off);
    if (lane == 0) rval[j] = p2 + benc[fi];
  }
  __syncthreads();

  // exact rank among candidates (tie-break: lower feature index first, matches np)
  for (int t2 = t; t2 < c; t2 += 256) {
    float v = rval[t2];
    int fi = ridx[t2];
    int rank = 0;
    for (int j = 0; j < c; ++j) {
      float vj = rval[j];
      if (vj > v || (vj == v && ridx[j] < fi)) ++rank;
    }
    if (rank < KSEL) { selv[rank] = v; seli[rank] = fi; }
  }
  __syncthreads();

  if (t < KSEL) {
    float v = fmaxf(selv[t], 0.f);
    selv[t] = v;
    crow[seli[t]] = v;
  }
  __syncthreads();

  for (int i = t; i < KSEL * DK; i += 256) {
    int s = i >> 6, e = i & 63;
    Vd[s][e] = Vdec[(size_t)seli[s] * DK + e];
    Wd[s][e] = Wdec[(size_t)seli[s] * DV + e];
  }
  __syncthreads();

  int k = t >> 2;
  int vb = (t & 3) << 4;
  float r[16];
  const float* bi = bias + k * DV + vb;
#pragma unroll
  for (int jj = 0; jj < 16; ++jj) r[jj] = bi[jj];
#pragma unroll
  for (int s = 0; s < KSEL; ++s) {
    float a = selv[s] * Vd[s][k];
#pragma unroll
    for (int jj = 0; jj < 16; ++jj) r[jj] = fmaf(a, Wd[s][vb + jj], r[jj]);
  }
  float m = 0.f;
  float* ro = recon + (size_t)b * DD + k * DV + vb;
#pragma unroll
  for (int jj = 0; jj < 16; ++jj) {
    float dd = r[jj] - xl[k * DV + vb + jj];
    m = fmaf(dd, dd, m);
    ro[jj] = r[jj];
  }
  red[t] = m;
  __syncthreads();
  for (int s2 = 128; s2 > 0; s2 >>= 1) {
    if (t < s2) red[t] += red[t + s2];
    __syncthreads();
  }
  if (t == 0) msepart[b] = red[0];
}

__global__ void k_mse(const float* __restrict__ msepart, float* __restrict__ out) {
  __shared__ float red[256];
  int t = threadIdx.x;
  float s = 0.f;
  for (int i = t; i < BATCH; i += 256) s += msepart[i];
  red[t] = s;
  __syncthreads();
  for (int k = 128; k > 0; k >>= 1) {
    if (t < k) red[t] += red[t + k];
    __syncthreads();
  }
  if (t == 0) out[0] = red[0] / (float)((size_t)BATCH * DD);
}

extern "C" void kernel_launch(void* const* d_in, const int* in_sizes, int n_in,
                              void* d_out, int out_size, void* d_ws, size_t ws_size,
                              hipStream_t stream) {
  const float* x    = (const float*)d_in[0];
  const float* Venc = (const float*)d_in[1];
  const float* Wenc = (const float*)d_in[2];
  const float* benc = (const float*)d_in[3];
  const float* Vdec = (const float*)d_in[4];
  const float* Wdec = (const float*)d_in[5];
  const float* bias = (const float*)d_in[6];

  float* out = (float*)d_out;
  float* recon  = out;                                   // [1024, 4096]
  float* coeffs = out + (size_t)BATCH * DD;              // [1024, 32768]
  float* mse    = coeffs + (size_t)BATCH * NFEAT;        // [1]

  char* wsp = (char*)d_ws;
  bf16* xb = (bf16*)wsp;                 wsp += (size_t)BATCH * DD * sizeof(bf16);
  bf16* Menc = (bf16*)wsp;               wsp += (size_t)NFEAT * DD * sizeof(bf16);
  int* cand_idx = (int*)wsp;             wsp += (size_t)BATCH * CAND_CAP * sizeof(int);
  int* cand_cnt = (int*)wsp;             wsp += (size_t)BATCH * sizeof(int);
  float* msepart = (float*)wsp;          wsp += (size_t)BATCH * sizeof(float);

  bf16* pre = (bf16*)coeffs;  // reuse coeffs region as bf16 pre scratch (zeroed by k_refine)

  hipFuncSetAttribute((const void*)k_gemm, hipFuncAttributeMaxDynamicSharedMemorySize,
                      GEMM_LDS);

  k_convert_x<<<(BATCH * DD) / (256 * 8), 256, 0, stream>>>(x, xb, BATCH * DD);
  k_build_menc<<<NFEAT, 256, 0, stream>>>(Venc, Wenc, Menc);
  k_gemm<<<(BATCH / BM) * (NFEAT / BN), 512, GEMM_LDS, stream>>>(xb, Menc, benc, pre);
  k_topk<<<BATCH, 256, 0, stream>>>((const unsigned short*)pre, cand_idx, cand_cnt);
  k_refine<<<BATCH, 256, 0, stream>>>(x, Venc, Wenc, benc, Vdec, Wdec, bias,
                                      cand_idx, cand_cnt, recon, coeffs, msepart);
  k_mse<<<1, 256, 0, stream>>>(msepart, mse);
}

// Round 6
// 480.625 us; speedup vs baseline: 1.2119x; 1.0239x over previous
//
#include <hip/hip_runtime.h>
#include <hip/hip_bf16.h>
#include <stdint.h>

#define NFEAT 32768
#define BATCH 1024
#define DK 64
#define DV 64
#define DD 4096
#define KSEL 32
#define CAND_CAP 512
#define CAND_TARGET 64

using bf16 = __bf16;
using bf16x8 = __attribute__((ext_vector_type(8))) __bf16;
using f32x4 = __attribute__((ext_vector_type(4))) float;

__device__ __forceinline__ void gload_lds16(const void* g, void* l) {
  __builtin_amdgcn_global_load_lds((const __attribute__((address_space(1))) void*)g,
                                   (__attribute__((address_space(3))) void*)l,
                                   16, 0, 0);
}

__device__ inline unsigned mono16(unsigned u) {
  return (u & 0x8000u) ? ((~u) & 0xFFFFu) : (u | 0x8000u);
}

// ---------------- x -> bf16 ----------------
__global__ void k_convert_x(const float* __restrict__ x, bf16* __restrict__ xb, int n) {
  int i = (blockIdx.x * blockDim.x + threadIdx.x) * 8;
  if (i >= n) return;
  float4 v0 = *reinterpret_cast<const float4*>(x + i);
  float4 v1 = *reinterpret_cast<const float4*>(x + i + 4);
  bf16x8 o;
  o[0] = (bf16)v0.x; o[1] = (bf16)v0.y; o[2] = (bf16)v0.z; o[3] = (bf16)v0.w;
  o[4] = (bf16)v1.x; o[5] = (bf16)v1.y; o[6] = (bf16)v1.z; o[7] = (bf16)v1.w;
  *reinterpret_cast<bf16x8*>(xb + i) = o;
}

// ---------------- M_enc[i][k*64+v] = V_enc[i][k] * W_enc[i][v] (bf16) ----------------
__global__ void k_build_menc(const float* __restrict__ Venc, const float* __restrict__ Wenc,
                             bf16* __restrict__ Menc) {
  int i = blockIdx.x;
  int t = threadIdx.x;
  int k = t >> 2;
  int vb = (t & 3) << 4;
  float vk = Venc[i * DK + k];
  const float* wrow = Wenc + i * DV + vb;
  float4 w0 = *reinterpret_cast<const float4*>(wrow);
  float4 w1 = *reinterpret_cast<const float4*>(wrow + 4);
  float4 w2 = *reinterpret_cast<const float4*>(wrow + 8);
  float4 w3 = *reinterpret_cast<const float4*>(wrow + 12);
  bf16x8 o0, o1;
  o0[0] = (bf16)(vk * w0.x); o0[1] = (bf16)(vk * w0.y);
  o0[2] = (bf16)(vk * w0.z); o0[3] = (bf16)(vk * w0.w);
  o0[4] = (bf16)(vk * w1.x); o0[5] = (bf16)(vk * w1.y);
  o0[6] = (bf16)(vk * w1.z); o0[7] = (bf16)(vk * w1.w);
  o1[0] = (bf16)(vk * w2.x); o1[1] = (bf16)(vk * w2.y);
  o1[2] = (bf16)(vk * w2.z); o1[3] = (bf16)(vk * w2.w);
  o1[4] = (bf16)(vk * w3.x); o1[5] = (bf16)(vk * w3.y);
  o1[6] = (bf16)(vk * w3.z); o1[7] = (bf16)(vk * w3.w);
  bf16* out = Menc + (size_t)i * DD + (t << 4);
  *reinterpret_cast<bf16x8*>(out) = o0;
  *reinterpret_cast<bf16x8*>(out + 8) = o1;
}

// ---------------- GEMM: pre[1024,32768] = bf16(xb @ Menc^T + b_enc) ----------------
// 256x256, BK=64, 8 waves (2M x 4N), double-buffered LDS, 3 phases/K-tile (snake):
// q0=(A0,B0) reads A0+B0, q1=(A0,B1) reads B1, q23=(A1,B1)+(A1,B0) reads A1.
// B frags held in regs across the K-tile -> 24 ds_read_b128/wave/K-tile (minimum).
// One barrier per phase; q23 drains lgkmcnt BEFORE its barrier so any wave past
// that barrier implies all reads of `cur` are complete (WAR-safe vs next writes).
#define BM 256
#define BN 256
#define BK 64
#define NT (DD / BK)          // 64 K-tiles
#define ABUF 32768            // 256*64*2
#define BUFSZ 65536           // A + B per K-tile
#define GEMM_LDS (2 * BUFSZ)  // 128 KiB

__device__ __forceinline__ void stage_chunk(const bf16* __restrict__ G, size_t rowbase,
                                            int k0, int c, int lane, char* dstbase) {
  const bf16* src = G + (rowbase + (size_t)(c * 8 + (lane >> 3))) * DD + k0 +
                    (((lane & 7) ^ (lane >> 3)) << 3);
  gload_lds16(src, dstbase + c * 1024);
}

__device__ __forceinline__ bf16x8 frag_ld(const char* base, int row, int colbyte) {
  return *reinterpret_cast<const bf16x8*>(base + row * 128 + (colbyte ^ ((row & 7) << 4)));
}

// half-tile chunk maps (idx = wave*2 + j, 0..15)
__device__ __forceinline__ int chA(int half, int idx) {
  return (idx < 8 ? idx : idx + 8) + half * 8;     // A0: rows 0-63 & 128-191
}
__device__ __forceinline__ int chB(int half, int idx) {
  return (idx >> 2) * 8 + (idx & 3) + half * 4;    // B0: first 32 rows of each 64-row band
}

#define LD_A(HALF)                                                                  \
  _Pragma("unroll") for (int m = 0; m < 4; ++m)                                     \
  _Pragma("unroll") for (int ks = 0; ks < 2; ++ks)                                  \
    afr[m][ks] = frag_ld(cur, wr * 128 + (HALF) * 64 + m * 16 + (lane & 15),        \
                         ks * 64 + ((lane >> 4) << 4));

// fills bfr[2*HALF + n]; all 4 n-frags stay live across the K-tile
#define LD_B(HALF)                                                                  \
  _Pragma("unroll") for (int n = 0; n < 2; ++n)                                     \
  _Pragma("unroll") for (int ks = 0; ks < 2; ++ks)                                  \
    bfr[(HALF) * 2 + n][ks] =                                                       \
        frag_ld(cur + ABUF, wc * 64 + (HALF) * 32 + n * 16 + (lane & 15),           \
                ks * 64 + ((lane >> 4) << 4));

#define ST_A(HALF, KT)                                                              \
  stage_chunk(A, brow, (KT) * BK, chA(HALF, wave * 2), lane, nxt);                  \
  stage_chunk(A, brow, (KT) * BK, chA(HALF, wave * 2 + 1), lane, nxt);

#define ST_B(HALF, KT)                                                              \
  stage_chunk(Bt, bcol, (KT) * BK, chB(HALF, wave * 2), lane, nxt + ABUF);          \
  stage_chunk(Bt, bcol, (KT) * BK, chB(HALF, wave * 2 + 1), lane, nxt + ABUF);

#define MFMA_Q(MBASE, NB)                                                           \
  asm volatile("s_waitcnt lgkmcnt(0)" ::: "memory");                                \
  __builtin_amdgcn_sched_barrier(0);                                                \
  __builtin_amdgcn_s_setprio(1);                                                    \
  _Pragma("unroll") for (int m = 0; m < 4; ++m)                                     \
  _Pragma("unroll") for (int n = 0; n < 2; ++n)                                     \
  _Pragma("unroll") for (int ks = 0; ks < 2; ++ks)                                  \
    acc[(MBASE) + m][(NB) + n] = __builtin_amdgcn_mfma_f32_16x16x32_bf16(           \
        afr[m][ks], bfr[(NB) + n][ks], acc[(MBASE) + m][(NB) + n], 0, 0, 0);        \
  __builtin_amdgcn_s_setprio(0);

#define VMC(N) asm volatile("s_waitcnt vmcnt(" #N ")" ::: "memory");
#define LGKM0 asm volatile("s_waitcnt lgkmcnt(0)" ::: "memory");
#define BARR                                                                        \
  asm volatile("s_barrier" ::: "memory");                                           \
  __builtin_amdgcn_sched_barrier(0);

__global__ __launch_bounds__(512, 2)
void k_gemm(const bf16* __restrict__ A, const bf16* __restrict__ Bt,
            const float* __restrict__ benc, bf16* __restrict__ C) {
  extern __shared__ char lds[];
  int tid = threadIdx.x;
  int wave = tid >> 6;
  int lane = tid & 63;
  int wr = wave >> 2;          // 0..1, 128 rows each
  int wc = wave & 3;           // 0..3, 64 cols each

  // XCD-grouped bijective remap (512 blocks, 512%8==0)
  int d = blockIdx.x;                  // 0..511
  int lw = (d & 7) * 64 + (d >> 3);
  int q = lw >> 2;                     // col panel 0..127
  int p = lw & 3;                      // row block 0..3
  size_t brow = (size_t)p * BM;
  size_t bcol = (size_t)q * BN;

  f32x4 acc[8][4] = {};
  bf16x8 afr[4][2];
  bf16x8 bfr[4][2];

  // prologue: stage tile 0 into buf0 (order B0,A0,B1,A1); publish B0,A0; barrier.
  {
    char* nxt = lds;
    ST_B(0, 0) ST_A(0, 0) ST_B(1, 0) ST_A(1, 0)
  }
  VMC(4)
  BARR

#pragma unroll 1
  for (int u = 0; u < NT - 1; ++u) {
    char* cur = lds + (u & 1) * BUFSZ;
    char* nxt = lds + ((u + 1) & 1) * BUFSZ;
    int k1 = u + 1;
    // q0: read A0,B0(u); stage B0(u+1); VMC(4) publishes B1(u) for q1
    LD_A(0) LD_B(0)
    ST_B(0, k1)
    VMC(4)
    BARR
    MFMA_Q(0, 0)
    // q1: read B1(u); stage A0(u+1); VMC(4) publishes A1(u) for q23
    LD_B(1)
    ST_A(0, k1)
    VMC(4)
    BARR
    MFMA_Q(0, 2)
    // q23: read A1(u); stage B1(u+1)+A1(u+1); VMC(4) publishes B0,A0(u+1) for next q0.
    // lgkm drained BEFORE the barrier: past-this-barrier => all reads of cur complete.
    LD_A(1)
    ST_B(1, k1) ST_A(1, k1)
    VMC(4)
    LGKM0
    BARR
    MFMA_Q(4, 2)
    MFMA_Q(4, 0)
  }

  // tail tile NT-1 (no staging); entry outstanding: B1(L),A1(L)
  {
    char* cur = lds + ((NT - 1) & 1) * BUFSZ;
    LD_A(0) LD_B(0)
    VMC(2)
    BARR
    MFMA_Q(0, 0)
    LD_B(1)
    VMC(0)
    BARR
    MFMA_Q(0, 2)
    LD_A(1)
    LGKM0
    BARR
    MFMA_Q(4, 2)
    MFMA_Q(4, 0)
  }

  // epilogue: C/D layout col = lane&15, row = (lane>>4)*4 + r; store bf16
#pragma unroll
  for (int nf = 0; nf < 4; ++nf) {
    size_t col = bcol + wc * 64 + nf * 16 + (lane & 15);
    float be = benc[col];
#pragma unroll
    for (int mf = 0; mf < 8; ++mf) {
      size_t row0 = brow + wr * 128 + mf * 16 + ((lane >> 4) << 2);
#pragma unroll
      for (int r = 0; r < 4; ++r)
        C[(row0 + r) * NFEAT + col] = (bf16)(acc[mf][nf][r] + be);
    }
  }
}

// ---------------- per-row candidate extraction from bf16 pre ----------------
__global__ void k_topk(const unsigned short* __restrict__ pre, int* __restrict__ cand_idx,
                       int* __restrict__ cand_cnt) {
  __shared__ int hist[8192];   // 13-bit bins of 16-bit monotonic code
  __shared__ int csum[256];
  __shared__ int sBstar;
  __shared__ int scount;
  int b = blockIdx.x;
  int t = threadIdx.x;
  const unsigned short* row = pre + (size_t)b * NFEAT;
  for (int i = t; i < 8192; i += 256) hist[i] = 0;
  if (t == 0) scount = 0;
  __syncthreads();

  for (int i = (t << 3); i < NFEAT; i += 2048) {
    uint4 v = *reinterpret_cast<const uint4*>(row + i);
#pragma unroll
    for (int j = 0; j < 4; ++j) {
      unsigned w = (&v.x)[j];
      atomicAdd(&hist[mono16(w & 0xFFFFu) >> 3], 1);
      atomicAdd(&hist[mono16(w >> 16) >> 3], 1);
    }
  }
  __syncthreads();

  int s = 0;
  for (int i = 0; i < 32; ++i) s += hist[t * 32 + i];
  csum[t] = s;
  __syncthreads();
  int suff = 0;
  for (int j = t + 1; j < 256; ++j) suff += csum[j];
  if (suff < CAND_TARGET && suff + s >= CAND_TARGET) {
    int acc = suff;
    int bstar = t * 32;
    for (int i = 31; i >= 0; --i) {
      acc += hist[t * 32 + i];
      if (acc >= CAND_TARGET) { bstar = t * 32 + i; break; }
    }
    sBstar = bstar;
  }
  __syncthreads();
  int Bstar = sBstar;
  int* cidx = cand_idx + b * CAND_CAP;

  for (int i = (t << 3); i < NFEAT; i += 2048) {
    uint4 v = *reinterpret_cast<const uint4*>(row + i);
#pragma unroll
    for (int j = 0; j < 4; ++j) {
      unsigned w = (&v.x)[j];
      int b0 = (int)(mono16(w & 0xFFFFu) >> 3);
      int b1 = (int)(mono16(w >> 16) >> 3);
      if (b0 >= Bstar) { int p2 = atomicAdd(&scount, 1); if (p2 < CAND_CAP) cidx[p2] = i + j * 2; }
      if (b1 >= Bstar) { int p2 = atomicAdd(&scount, 1); if (p2 < CAND_CAP) cidx[p2] = i + j * 2 + 1; }
    }
  }
  __syncthreads();
  if (t == 0) cand_cnt[b] = (scount < CAND_CAP) ? scount : CAND_CAP;
}

// ---------------- fp32 refine + exact top-32 + zero+scatter + decode + mse partial ----------------
__global__ void k_refine(const float* __restrict__ x,
                         const float* __restrict__ Venc,
                         const float* __restrict__ Wenc,
                         const float* __restrict__ benc,
                         const float* __restrict__ Vdec,
                         const float* __restrict__ Wdec,
                         const float* __restrict__ bias,
                         const int* __restrict__ cand_idx,
                         const int* __restrict__ cand_cnt,
                         float* __restrict__ recon,
                         float* __restrict__ coeffs,
                         float* __restrict__ msepart) {
  __shared__ float xl[DD];
  __shared__ float rval[CAND_CAP];
  __shared__ int ridx[CAND_CAP];
  __shared__ float selv[KSEL];
  __shared__ int seli[KSEL];
  __shared__ float Vd[KSEL][DK];
  __shared__ float Wd[KSEL][DV];
  __shared__ float red[256];

  int b = blockIdx.x;
  int t = threadIdx.x;
  int wave = t >> 6;
  int lane = t & 63;

  // zero this row of coeffs (pre is dead after k_topk)
  float* crow = coeffs + (size_t)b * NFEAT;
  float4 z4 = {0.f, 0.f, 0.f, 0.f};
  for (int i = (t << 2); i < NFEAT; i += 1024)
    *reinterpret_cast<float4*>(crow + i) = z4;

  const float* xr = x + (size_t)b * DD;
  for (int i = (t << 2); i < DD; i += 1024)
    *reinterpret_cast<float4*>(xl + i) = *reinterpret_cast<const float4*>(xr + i);

  int c = cand_cnt[b];
  if (c > CAND_CAP) c = CAND_CAP;
  for (int i = t; i < c; i += 256) ridx[i] = cand_idx[b * CAND_CAP + i];
  __syncthreads();

  // exact fp32 pre for each candidate
  for (int j = wave; j < c; j += 4) {
    int fi = ridx[j];
    const float* vr = Venc + (size_t)fi * DK;
    float acc = 0.f;
#pragma unroll
    for (int kk = 0; kk < DK; kk += 4) {
      float4 v4 = *reinterpret_cast<const float4*>(vr + kk);
      acc = fmaf(xl[(kk + 0) * DV + lane], v4.x, acc);
      acc = fmaf(xl[(kk + 1) * DV + lane], v4.y, acc);
      acc = fmaf(xl[(kk + 2) * DV + lane], v4.z, acc);
      acc = fmaf(xl[(kk + 3) * DV + lane], v4.w, acc);
    }
    float p2 = acc * Wenc[(size_t)fi * DV + lane];
#pragma unroll
    for (int off = 1; off < 64; off <<= 1) p2 += __shfl_xor(p2, off);
    if (lane == 0) rval[j] = p2 + benc[fi];
  }
  __syncthreads();

  // exact rank among candidates (tie-break: lower feature index first, matches np)
  for (int t2 = t; t2 < c; t2 += 256) {
    float v = rval[t2];
    int fi = ridx[t2];
    int rank = 0;
    for (int j = 0; j < c; ++j) {
      float vj = rval[j];
      if (vj > v || (vj == v && ridx[j] < fi)) ++rank;
    }
    if (rank < KSEL) { selv[rank] = v; seli[rank] = fi; }
  }
  __syncthreads();

  if (t < KSEL) {
    float v = fmaxf(selv[t], 0.f);
    selv[t] = v;
    crow[seli[t]] = v;
  }
  __syncthreads();

  for (int i = t; i < KSEL * DK; i += 256) {
    int s = i >> 6, e = i & 63;
    Vd[s][e] = Vdec[(size_t)seli[s] * DK + e];
    Wd[s][e] = Wdec[(size_t)seli[s] * DV + e];
  }
  __syncthreads();

  int k = t >> 2;
  int vb = (t & 3) << 4;
  float r[16];
  const float* bi = bias + k * DV + vb;
#pragma unroll
  for (int jj = 0; jj < 16; ++jj) r[jj] = bi[jj];
#pragma unroll
  for (int s = 0; s < KSEL; ++s) {
    float a = selv[s] * Vd[s][k];
#pragma unroll
    for (int jj = 0; jj < 16; ++jj) r[jj] = fmaf(a, Wd[s][vb + jj], r[jj]);
  }
  float m = 0.f;
  float* ro = recon + (size_t)b * DD + k * DV + vb;
#pragma unroll
  for (int jj = 0; jj < 16; ++jj) {
    float dd = r[jj] - xl[k * DV + vb + jj];
    m = fmaf(dd, dd, m);
    ro[jj] = r[jj];
  }
  red[t] = m;
  __syncthreads();
  for (int s2 = 128; s2 > 0; s2 >>= 1) {
    if (t < s2) red[t] += red[t + s2];
    __syncthreads();
  }
  if (t == 0) msepart[b] = red[0];
}

__global__ void k_mse(const float* __restrict__ msepart, float* __restrict__ out) {
  __shared__ float red[256];
  int t = threadIdx.x;
  float s = 0.f;
  for (int i = t; i < BATCH; i += 256) s += msepart[i];
  red[t] = s;
  __syncthreads();
  for (int k = 128; k > 0; k >>= 1) {
    if (t < k) red[t] += red[t + k];
    __syncthreads();
  }
  if (t == 0) out[0] = red[0] / (float)((size_t)BATCH * DD);
}

extern "C" void kernel_launch(void* const* d_in, const int* in_sizes, int n_in,
                              void* d_out, int out_size, void* d_ws, size_t ws_size,
                              hipStream_t stream) {
  const float* x    = (const float*)d_in[0];
  const float* Venc = (const float*)d_in[1];
  const float* Wenc = (const float*)d_in[2];
  const float* benc = (const float*)d_in[3];
  const float* Vdec = (const float*)d_in[4];
  const float* Wdec = (const float*)d_in[5];
  const float* bias = (const float*)d_in[6];

  float* out = (float*)d_out;
  float* recon  = out;                                   // [1024, 4096]
  float* coeffs = out + (size_t)BATCH * DD;              // [1024, 32768]
  float* mse    = coeffs + (size_t)BATCH * NFEAT;        // [1]

  char* wsp = (char*)d_ws;
  bf16* xb = (bf16*)wsp;                 wsp += (size_t)BATCH * DD * sizeof(bf16);
  bf16* Menc = (bf16*)wsp;               wsp += (size_t)NFEAT * DD * sizeof(bf16);
  int* cand_idx = (int*)wsp;             wsp += (size_t)BATCH * CAND_CAP * sizeof(int);
  int* cand_cnt = (int*)wsp;             wsp += (size_t)BATCH * sizeof(int);
  float* msepart = (float*)wsp;          wsp += (size_t)BATCH * sizeof(float);

  bf16* pre = (bf16*)coeffs;  // reuse coeffs region as bf16 pre scratch (zeroed by k_refine)

  hipFuncSetAttribute((const void*)k_gemm, hipFuncAttributeMaxDynamicSharedMemorySize,
                      GEMM_LDS);

  k_convert_x<<<(BATCH * DD) / (256 * 8), 256, 0, stream>>>(x, xb, BATCH * DD);
  k_build_menc<<<NFEAT, 256, 0, stream>>>(Venc, Wenc, Menc);
  k_gemm<<<(BATCH / BM) * (NFEAT / BN), 512, GEMM_LDS, stream>>>(xb, Menc, benc, pre);
  k_topk<<<BATCH, 256, 0, stream>>>((const unsigned short*)pre, cand_idx, cand_cnt);
  k_refine<<<BATCH, 256, 0, stream>>>(x, Venc, Wenc, benc, Vdec, Wdec, bias,
                                      cand_idx, cand_cnt, recon, coeffs, msepart);
  k_mse<<<1, 256, 0, stream>>>(msepart, mse);
}

// Round 7
// 395.609 us; speedup vs baseline: 1.4723x; 1.2149x over previous
//
#include <hip/hip_runtime.h>
#include <hip/hip_bf16.h>
#include <hip/hip_fp8.h>
#include <stdint.h>

#define NFEAT 32768
#define BATCH 1024
#define DK 64
#define DV 64
#define DD 4096
#define KSEL 32
#define CAND_CAP 512
#define CAND_TARGET 128

using bf16 = __bf16;
using bf16x8 = __attribute__((ext_vector_type(8))) __bf16;
using f32x4 = __attribute__((ext_vector_type(4))) float;
using f32x16 = __attribute__((ext_vector_type(16))) float;
using i32x4 = __attribute__((ext_vector_type(4))) int;
using i32x8 = __attribute__((ext_vector_type(8))) int;

__device__ __forceinline__ void gload_lds16(const void* g, void* l) {
  __builtin_amdgcn_global_load_lds((const __attribute__((address_space(1))) void*)g,
                                   (__attribute__((address_space(3))) void*)l,
                                   16, 0, 0);
}

__device__ inline unsigned mono16(unsigned u) {
  return (u & 0x8000u) ? ((~u) & 0xFFFFu) : (u | 0x8000u);
}

// ---------------- x -> fp8 e4m3 ----------------
__global__ void k_convert_x(const float* __restrict__ x, unsigned char* __restrict__ xb, int n) {
  int i = (blockIdx.x * blockDim.x + threadIdx.x) * 16;
  if (i >= n) return;
  union { unsigned char b[16]; uint4 u; } o;
#pragma unroll
  for (int j = 0; j < 16; j += 4) {
    float4 v = *reinterpret_cast<const float4*>(x + i + j);
    o.b[j + 0] = __hip_fp8_e4m3(v.x).__x;
    o.b[j + 1] = __hip_fp8_e4m3(v.y).__x;
    o.b[j + 2] = __hip_fp8_e4m3(v.z).__x;
    o.b[j + 3] = __hip_fp8_e4m3(v.w).__x;
  }
  *reinterpret_cast<uint4*>(xb + i) = o.u;
}

// ---------------- M_enc fp8: 16 * V_enc[i][k] * W_enc[i][v] (scale undone in epilogue) ----------------
__global__ void k_build_menc(const float* __restrict__ Venc, const float* __restrict__ Wenc,
                             unsigned char* __restrict__ Menc) {
  int i = blockIdx.x;
  int t = threadIdx.x;
  int k = t >> 2;
  int vb = (t & 3) << 4;
  float vk = 16.0f * Venc[i * DK + k];
  const float* wrow = Wenc + i * DV + vb;
  union { unsigned char b[16]; uint4 u; } o;
#pragma unroll
  for (int j = 0; j < 16; j += 4) {
    float4 w = *reinterpret_cast<const float4*>(wrow + j);
    o.b[j + 0] = __hip_fp8_e4m3(vk * w.x).__x;
    o.b[j + 1] = __hip_fp8_e4m3(vk * w.y).__x;
    o.b[j + 2] = __hip_fp8_e4m3(vk * w.z).__x;
    o.b[j + 3] = __hip_fp8_e4m3(vk * w.w).__x;
  }
  *reinterpret_cast<uint4*>(Menc + (size_t)i * DD + (t << 4)) = o.u;
}

// ---------------- GEMM: pre = bf16((x8 @ Menc8^T)/16 + b_enc), MX-fp8 MFMA ----------------
// 256x256 tile, BK=128 bytes, 8 waves (2M x 4N), double-buffered LDS, snake phases
// identical to the verified bf16 schedule. Rows are 128 B -> same st_16x32 XOR swizzle,
// same chunk maps, same VMC(4)/barrier proof. mfma_scale_f32_32x32x64_f8f6f4, scales=1.0.
#define BM 256
#define BN 256
#define BKB 128               // K-bytes (= fp8 elems) per tile
#define NT (DD / BKB)         // 32 K-tiles
#define ABUF 32768            // 256 rows * 128 B
#define BUFSZ 65536           // A + B per K-tile
#define GEMM_LDS (2 * BUFSZ)  // 128 KiB

__device__ __forceinline__ void stage_chunk(const unsigned char* __restrict__ G, size_t rowbase,
                                            int kb0, int c, int lane, char* dstbase) {
  const unsigned char* src = G + (rowbase + (size_t)(c * 8 + (lane >> 3))) * DD + kb0 +
                             (((lane & 7) ^ (lane >> 3)) << 4);
  gload_lds16(src, dstbase + c * 1024);
}

__device__ __forceinline__ i32x8 frag_ld8(const char* base, int row, int col) {
  i32x4 lo = *reinterpret_cast<const i32x4*>(base + row * 128 + (col ^ ((row & 7) << 4)));
  i32x4 hi = *reinterpret_cast<const i32x4*>(base + row * 128 + ((col + 16) ^ ((row & 7) << 4)));
  i32x8 r;
  r[0] = lo[0]; r[1] = lo[1]; r[2] = lo[2]; r[3] = lo[3];
  r[4] = hi[0]; r[5] = hi[1]; r[6] = hi[2]; r[7] = hi[3];
  return r;
}

// half-tile chunk maps (idx = wave*2 + j, 0..15) — unchanged geometry
__device__ __forceinline__ int chA(int half, int idx) {
  return (idx < 8 ? idx : idx + 8) + half * 8;     // A-half0: rows 0-63 & 128-191
}
__device__ __forceinline__ int chB(int half, int idx) {
  return (idx >> 2) * 8 + (idx & 3) + half * 4;    // B-half0: first 32 rows of each 64-band
}

// A frags for m-half H: local m-blocks 0/1 (32 rows each), kh 0/1 (64 k-bytes each)
#define LD_A(H)                                                                     \
  _Pragma("unroll") for (int mb = 0; mb < 2; ++mb)                                  \
  _Pragma("unroll") for (int kh = 0; kh < 2; ++kh)                                  \
    afr[mb][kh] = frag_ld8(cur, wr * 128 + (H) * 64 + mb * 32 + (lane & 31),        \
                           kh * 64 + ((lane >> 5) << 5));

// B frag for n-block H (32 cols), both kh; persists across the K-tile
#define LD_B(H)                                                                     \
  _Pragma("unroll") for (int kh = 0; kh < 2; ++kh)                                  \
    bfr[(H)][kh] = frag_ld8(cur + ABUF, wc * 64 + (H) * 32 + (lane & 31),           \
                            kh * 64 + ((lane >> 5) << 5));

#define ST_A(HALF, KT)                                                              \
  stage_chunk(A, brow, (KT) * BKB, chA(HALF, wave * 2), lane, nxt);                 \
  stage_chunk(A, brow, (KT) * BKB, chA(HALF, wave * 2 + 1), lane, nxt);

#define ST_B(HALF, KT)                                                              \
  stage_chunk(Bt, bcol, (KT) * BKB, chB(HALF, wave * 2), lane, nxt + ABUF);         \
  stage_chunk(Bt, bcol, (KT) * BKB, chB(HALF, wave * 2 + 1), lane, nxt + ABUF);

#define MFMA_Q(MH, NB)                                                              \
  asm volatile("s_waitcnt lgkmcnt(0)" ::: "memory");                                \
  __builtin_amdgcn_sched_barrier(0);                                                \
  __builtin_amdgcn_s_setprio(1);                                                    \
  _Pragma("unroll") for (int mb = 0; mb < 2; ++mb)                                  \
  _Pragma("unroll") for (int kh = 0; kh < 2; ++kh)                                  \
    acc[(MH) * 2 + mb][NB] = __builtin_amdgcn_mfma_scale_f32_32x32x64_f8f6f4(       \
        afr[mb][kh], bfr[NB][kh], acc[(MH) * 2 + mb][NB], 0, 0, 0, 0x7F, 0, 0x7F);  \
  __builtin_amdgcn_s_setprio(0);

#define VMC(N) asm volatile("s_waitcnt vmcnt(" #N ")" ::: "memory");
#define LGKM0 asm volatile("s_waitcnt lgkmcnt(0)" ::: "memory");
#define BARR                                                                        \
  asm volatile("s_barrier" ::: "memory");                                           \
  __builtin_amdgcn_sched_barrier(0);

__global__ __launch_bounds__(512, 2)
void k_gemm(const unsigned char* __restrict__ A, const unsigned char* __restrict__ Bt,
            const float* __restrict__ benc, bf16* __restrict__ C) {
  extern __shared__ char lds[];
  int tid = threadIdx.x;
  int wave = tid >> 6;
  int lane = tid & 63;
  int wr = wave >> 2;          // 0..1, 128 rows each
  int wc = wave & 3;           // 0..3, 64 cols each

  // XCD-grouped bijective remap (512 blocks, 512%8==0)
  int d = blockIdx.x;                  // 0..511
  int lw = (d & 7) * 64 + (d >> 3);
  int q = lw >> 2;                     // col panel 0..127
  int p = lw & 3;                      // row block 0..3
  size_t brow = (size_t)p * BM;
  size_t bcol = (size_t)q * BN;

  f32x16 acc[4][2] = {};
  i32x8 afr[2][2];
  i32x8 bfr[2][2];

  // prologue: stage tile 0 (order B0,A0,B1,A1); publish B0,A0; barrier.
  {
    char* nxt = lds;
    ST_B(0, 0) ST_A(0, 0) ST_B(1, 0) ST_A(1, 0)
  }
  VMC(4)
  BARR

#pragma unroll 1
  for (int u = 0; u < NT - 1; ++u) {
    char* cur = lds + (u & 1) * BUFSZ;
    char* nxt = lds + ((u + 1) & 1) * BUFSZ;
    int k1 = u + 1;
    // q0: read A-h0, B-n0; stage B0(u+1); VMC(4) publishes B1(u) for q1
    LD_A(0) LD_B(0)
    ST_B(0, k1)
    VMC(4)
    BARR
    MFMA_Q(0, 0)
    // q1: read B-n1; stage A0(u+1); VMC(4) publishes A1(u) for q23
    LD_B(1)
    ST_A(0, k1)
    VMC(4)
    BARR
    MFMA_Q(0, 1)
    // q23: read A-h1; stage B1,A1(u+1); VMC(4) publishes B0,A0(u+1); lgkm drained pre-barrier
    LD_A(1)
    ST_B(1, k1) ST_A(1, k1)
    VMC(4)
    LGKM0
    BARR
    MFMA_Q(1, 1)
    MFMA_Q(1, 0)
  }

  // tail tile NT-1 (no staging); entry outstanding: B1(L),A1(L)
  {
    char* cur = lds + ((NT - 1) & 1) * BUFSZ;
    LD_A(0) LD_B(0)
    VMC(2)
    BARR
    MFMA_Q(0, 0)
    LD_B(1)
    VMC(0)
    BARR
    MFMA_Q(0, 1)
    LD_A(1)
    LGKM0
    BARR
    MFMA_Q(1, 1)
    MFMA_Q(1, 0)
  }

  // epilogue: 32x32 C/D layout col=lane&31, row=(reg&3)+8*(reg>>2)+4*(lane>>5); descale 1/16
#pragma unroll
  for (int nb = 0; nb < 2; ++nb) {
    size_t col = bcol + wc * 64 + nb * 32 + (lane & 31);
    float be = benc[col];
#pragma unroll
    for (int MB = 0; MB < 4; ++MB) {
      size_t row0 = brow + wr * 128 + MB * 32 + ((lane >> 5) << 2);
#pragma unroll
      for (int reg = 0; reg < 16; ++reg) {
        size_t row = row0 + (reg & 3) + ((reg >> 2) << 3);
        C[row * NFEAT + col] = (bf16)(acc[MB][nb][reg] * 0.0625f + be);
      }
    }
  }
}

// ---------------- per-row candidate extraction from bf16 pre ----------------
__global__ void k_topk(const unsigned short* __restrict__ pre, int* __restrict__ cand_idx,
                       int* __restrict__ cand_cnt) {
  __shared__ int hist[8192];   // 13-bit bins of 16-bit monotonic code
  __shared__ int csum[256];
  __shared__ int sBstar;
  __shared__ int scount;
  int b = blockIdx.x;
  int t = threadIdx.x;
  const unsigned short* row = pre + (size_t)b * NFEAT;
  for (int i = t; i < 8192; i += 256) hist[i] = 0;
  if (t == 0) scount = 0;
  __syncthreads();

  for (int i = (t << 3); i < NFEAT; i += 2048) {
    uint4 v = *reinterpret_cast<const uint4*>(row + i);
#pragma unroll
    for (int j = 0; j < 4; ++j) {
      unsigned w = (&v.x)[j];
      atomicAdd(&hist[mono16(w & 0xFFFFu) >> 3], 1);
      atomicAdd(&hist[mono16(w >> 16) >> 3], 1);
    }
  }
  __syncthreads();

  int s = 0;
  for (int i = 0; i < 32; ++i) s += hist[t * 32 + i];
  csum[t] = s;
  __syncthreads();
  int suff = 0;
  for (int j = t + 1; j < 256; ++j) suff += csum[j];
  if (suff < CAND_TARGET && suff + s >= CAND_TARGET) {
    int acc = suff;
    int bstar = t * 32;
    for (int i = 31; i >= 0; --i) {
      acc += hist[t * 32 + i];
      if (acc >= CAND_TARGET) { bstar = t * 32 + i; break; }
    }
    sBstar = bstar;
  }
  __syncthreads();
  int Bstar = sBstar;
  int* cidx = cand_idx + b * CAND_CAP;

  for (int i = (t << 3); i < NFEAT; i += 2048) {
    uint4 v = *reinterpret_cast<const uint4*>(row + i);
#pragma unroll
    for (int j = 0; j < 4; ++j) {
      unsigned w = (&v.x)[j];
      int b0 = (int)(mono16(w & 0xFFFFu) >> 3);
      int b1 = (int)(mono16(w >> 16) >> 3);
      if (b0 >= Bstar) { int p2 = atomicAdd(&scount, 1); if (p2 < CAND_CAP) cidx[p2] = i + j * 2; }
      if (b1 >= Bstar) { int p2 = atomicAdd(&scount, 1); if (p2 < CAND_CAP) cidx[p2] = i + j * 2 + 1; }
    }
  }
  __syncthreads();
  if (t == 0) cand_cnt[b] = (scount < CAND_CAP) ? scount : CAND_CAP;
}

// ---------------- fp32 refine + exact top-32 + zero+scatter + decode + mse partial ----------------
__global__ void k_refine(const float* __restrict__ x,
                         const float* __restrict__ Venc,
                         const float* __restrict__ Wenc,
                         const float* __restrict__ benc,
                         const float* __restrict__ Vdec,
                         const float* __restrict__ Wdec,
                         const float* __restrict__ bias,
                         const int* __restrict__ cand_idx,
                         const int* __restrict__ cand_cnt,
                         float* __restrict__ recon,
                         float* __restrict__ coeffs,
                         float* __restrict__ msepart) {
  __shared__ float xl[DD];
  __shared__ float rval[CAND_CAP];
  __shared__ int ridx[CAND_CAP];
  __shared__ float selv[KSEL];
  __shared__ int seli[KSEL];
  __shared__ float Vd[KSEL][DK];
  __shared__ float Wd[KSEL][DV];
  __shared__ float red[256];

  int b = blockIdx.x;
  int t = threadIdx.x;
  int wave = t >> 6;
  int lane = t & 63;

  // zero this row of coeffs (pre is dead after k_topk)
  float* crow = coeffs + (size_t)b * NFEAT;
  float4 z4 = {0.f, 0.f, 0.f, 0.f};
  for (int i = (t << 2); i < NFEAT; i += 1024)
    *reinterpret_cast<float4*>(crow + i) = z4;

  const float* xr = x + (size_t)b * DD;
  for (int i = (t << 2); i < DD; i += 1024)
    *reinterpret_cast<float4*>(xl + i) = *reinterpret_cast<const float4*>(xr + i);

  int c = cand_cnt[b];
  if (c > CAND_CAP) c = CAND_CAP;
  for (int i = t; i < c; i += 256) ridx[i] = cand_idx[b * CAND_CAP + i];
  __syncthreads();

  // exact fp32 pre for each candidate
  for (int j = wave; j < c; j += 4) {
    int fi = ridx[j];
    const float* vr = Venc + (size_t)fi * DK;
    float acc = 0.f;
#pragma unroll
    for (int kk = 0; kk < DK; kk += 4) {
      float4 v4 = *reinterpret_cast<const float4*>(vr + kk);
      acc = fmaf(xl[(kk + 0) * DV + lane], v4.x, acc);
      acc = fmaf(xl[(kk + 1) * DV + lane], v4.y, acc);
      acc = fmaf(xl[(kk + 2) * DV + lane], v4.z, acc);
      acc = fmaf(xl[(kk + 3) * DV + lane], v4.w, acc);
    }
    float p2 = acc * Wenc[(size_t)fi * DV + lane];
#pragma unroll
    for (int off = 1; off < 64; off <<= 1) p2 += __shfl_xor(p2, off);
    if (lane == 0) rval[j] = p2 + benc[fi];
  }
  __syncthreads();

  // exact rank among candidates (tie-break: lower feature index first, matches np)
  for (int t2 = t; t2 < c; t2 += 256) {
    float v = rval[t2];
    int fi = ridx[t2];
    int rank = 0;
    for (int j = 0; j < c; ++j) {
      float vj = rval[j];
      if (vj > v || (vj == v && ridx[j] < fi)) ++rank;
    }
    if (rank < KSEL) { selv[rank] = v; seli[rank] = fi; }
  }
  __syncthreads();

  if (t < KSEL) {
    float v = fmaxf(selv[t], 0.f);
    selv[t] = v;
    crow[seli[t]] = v;
  }
  __syncthreads();

  for (int i = t; i < KSEL * DK; i += 256) {
    int s = i >> 6, e = i & 63;
    Vd[s][e] = Vdec[(size_t)seli[s] * DK + e];
    Wd[s][e] = Wdec[(size_t)seli[s] * DV + e];
  }
  __syncthreads();

  int k = t >> 2;
  int vb = (t & 3) << 4;
  float r[16];
  const float* bi = bias + k * DV + vb;
#pragma unroll
  for (int jj = 0; jj < 16; ++jj) r[jj] = bi[jj];
#pragma unroll
  for (int s = 0; s < KSEL; ++s) {
    float a = selv[s] * Vd[s][k];
#pragma unroll
    for (int jj = 0; jj < 16; ++jj) r[jj] = fmaf(a, Wd[s][vb + jj], r[jj]);
  }
  float m = 0.f;
  float* ro = recon + (size_t)b * DD + k * DV + vb;
#pragma unroll
  for (int jj = 0; jj < 16; ++jj) {
    float dd = r[jj] - xl[k * DV + vb + jj];
    m = fmaf(dd, dd, m);
    ro[jj] = r[jj];
  }
  red[t] = m;
  __syncthreads();
  for (int s2 = 128; s2 > 0; s2 >>= 1) {
    if (t < s2) red[t] += red[t + s2];
    __syncthreads();
  }
  if (t == 0) msepart[b] = red[0];
}

__global__ void k_mse(const float* __restrict__ msepart, float* __restrict__ out) {
  __shared__ float red[256];
  int t = threadIdx.x;
  float s = 0.f;
  for (int i = t; i < BATCH; i += 256) s += msepart[i];
  red[t] = s;
  __syncthreads();
  for (int k = 128; k > 0; k >>= 1) {
    if (t < k) red[t] += red[t + k];
    __syncthreads();
  }
  if (t == 0) out[0] = red[0] / (float)((size_t)BATCH * DD);
}

extern "C" void kernel_launch(void* const* d_in, const int* in_sizes, int n_in,
                              void* d_out, int out_size, void* d_ws, size_t ws_size,
                              hipStream_t stream) {
  const float* x    = (const float*)d_in[0];
  const float* Venc = (const float*)d_in[1];
  const float* Wenc = (const float*)d_in[2];
  const float* benc = (const float*)d_in[3];
  const float* Vdec = (const float*)d_in[4];
  const float* Wdec = (const float*)d_in[5];
  const float* bias = (const float*)d_in[6];

  float* out = (float*)d_out;
  float* recon  = out;                                   // [1024, 4096]
  float* coeffs = out + (size_t)BATCH * DD;              // [1024, 32768]
  float* mse    = coeffs + (size_t)BATCH * NFEAT;        // [1]

  char* wsp = (char*)d_ws;
  unsigned char* xb8 = (unsigned char*)wsp;   wsp += (size_t)BATCH * DD;
  unsigned char* Menc8 = (unsigned char*)wsp; wsp += (size_t)NFEAT * DD;
  int* cand_idx = (int*)wsp;                  wsp += (size_t)BATCH * CAND_CAP * sizeof(int);
  int* cand_cnt = (int*)wsp;                  wsp += (size_t)BATCH * sizeof(int);
  float* msepart = (float*)wsp;               wsp += (size_t)BATCH * sizeof(float);

  bf16* pre = (bf16*)coeffs;  // reuse coeffs region as bf16 pre scratch (zeroed by k_refine)

  hipFuncSetAttribute((const void*)k_gemm, hipFuncAttributeMaxDynamicSharedMemorySize,
                      GEMM_LDS);

  k_convert_x<<<(BATCH * DD) / (256 * 16), 256, 0, stream>>>(x, xb8, BATCH * DD);
  k_build_menc<<<NFEAT, 256, 0, stream>>>(Venc, Wenc, Menc8);
  k_gemm<<<(BATCH / BM) * (NFEAT / BN), 512, GEMM_LDS, stream>>>(xb8, Menc8, benc, pre);
  k_topk<<<BATCH, 256, 0, stream>>>((const unsigned short*)pre, cand_idx, cand_cnt);
  k_refine<<<BATCH, 256, 0, stream>>>(x, Venc, Wenc, benc, Vdec, Wdec, bias,
                                      cand_idx, cand_cnt, recon, coeffs, msepart);
  k_mse<<<1, 256, 0, stream>>>(msepart, mse);
}

// Round 8
// 309.225 us; speedup vs baseline: 1.8836x; 1.2794x over previous
//
#include <hip/hip_runtime.h>
#include <hip/hip_bf16.h>
#include <hip/hip_fp8.h>
#include <stdint.h>

#define NFEAT 32768
#define BATCH 1024
#define DK 64
#define DV 64
#define DD 4096
#define KSEL 32
#define CAND_CAP 512
#define CAND_TARGET 128

using bf16 = __bf16;
using bf16x8 = __attribute__((ext_vector_type(8))) __bf16;
using f32x4 = __attribute__((ext_vector_type(4))) float;
using f32x16 = __attribute__((ext_vector_type(16))) float;
using i32x4 = __attribute__((ext_vector_type(4))) int;
using i32x8 = __attribute__((ext_vector_type(8))) int;

__device__ __forceinline__ void gload_lds16(const void* g, void* l) {
  __builtin_amdgcn_global_load_lds((const __attribute__((address_space(1))) void*)g,
                                   (__attribute__((address_space(3))) void*)l,
                                   16, 0, 0);
}

__device__ inline unsigned mono16(unsigned u) {
  return (u & 0x8000u) ? ((~u) & 0xFFFFu) : (u | 0x8000u);
}

// ---------------- x -> fp8 e4m3 ----------------
__global__ void k_convert_x(const float* __restrict__ x, unsigned char* __restrict__ xb, int n) {
  int i = (blockIdx.x * blockDim.x + threadIdx.x) * 16;
  if (i >= n) return;
  union { unsigned char b[16]; uint4 u; } o;
#pragma unroll
  for (int j = 0; j < 16; j += 4) {
    float4 v = *reinterpret_cast<const float4*>(x + i + j);
    o.b[j + 0] = __hip_fp8_e4m3(v.x).__x;
    o.b[j + 1] = __hip_fp8_e4m3(v.y).__x;
    o.b[j + 2] = __hip_fp8_e4m3(v.z).__x;
    o.b[j + 3] = __hip_fp8_e4m3(v.w).__x;
  }
  *reinterpret_cast<uint4*>(xb + i) = o.u;
}

// ---------------- M_enc fp8: 16 * V_enc[i][k] * W_enc[i][v] (scale undone in epilogue) ----------------
__global__ void k_build_menc(const float* __restrict__ Venc, const float* __restrict__ Wenc,
                             unsigned char* __restrict__ Menc) {
  int i = blockIdx.x;
  int t = threadIdx.x;
  int k = t >> 2;
  int vb = (t & 3) << 4;
  float vk = 16.0f * Venc[i * DK + k];
  const float* wrow = Wenc + i * DV + vb;
  union { unsigned char b[16]; uint4 u; } o;
#pragma unroll
  for (int j = 0; j < 16; j += 4) {
    float4 w = *reinterpret_cast<const float4*>(wrow + j);
    o.b[j + 0] = __hip_fp8_e4m3(vk * w.x).__x;
    o.b[j + 1] = __hip_fp8_e4m3(vk * w.y).__x;
    o.b[j + 2] = __hip_fp8_e4m3(vk * w.z).__x;
    o.b[j + 3] = __hip_fp8_e4m3(vk * w.w).__x;
  }
  *reinterpret_cast<uint4*>(Menc + (size_t)i * DD + (t << 4)) = o.u;
}

// ---------------- GEMM: pre = bf16((x8 @ Menc8^T)/16 + b_enc), MX-fp8 MFMA ----------------
#define BM 256
#define BN 256
#define BKB 128               // K-bytes (= fp8 elems) per tile
#define NT (DD / BKB)         // 32 K-tiles
#define ABUF 32768            // 256 rows * 128 B
#define BUFSZ 65536           // A + B per K-tile
#define GEMM_LDS (2 * BUFSZ)  // 128 KiB

__device__ __forceinline__ void stage_chunk(const unsigned char* __restrict__ G, size_t rowbase,
                                            int kb0, int c, int lane, char* dstbase) {
  const unsigned char* src = G + (rowbase + (size_t)(c * 8 + (lane >> 3))) * DD + kb0 +
                             (((lane & 7) ^ (lane >> 3)) << 4);
  gload_lds16(src, dstbase + c * 1024);
}

__device__ __forceinline__ i32x8 frag_ld8(const char* base, int row, int col) {
  i32x4 lo = *reinterpret_cast<const i32x4*>(base + row * 128 + (col ^ ((row & 7) << 4)));
  i32x4 hi = *reinterpret_cast<const i32x4*>(base + row * 128 + ((col + 16) ^ ((row & 7) << 4)));
  i32x8 r;
  r[0] = lo[0]; r[1] = lo[1]; r[2] = lo[2]; r[3] = lo[3];
  r[4] = hi[0]; r[5] = hi[1]; r[6] = hi[2]; r[7] = hi[3];
  return r;
}

// half-tile chunk maps (idx = wave*2 + j, 0..15)
__device__ __forceinline__ int chA(int half, int idx) {
  return (idx < 8 ? idx : idx + 8) + half * 8;     // A-half0: rows 0-63 & 128-191
}
__device__ __forceinline__ int chB(int half, int idx) {
  return (idx >> 2) * 8 + (idx & 3) + half * 4;    // B-half0: first 32 rows of each 64-band
}

#define LD_A(H)                                                                     \
  _Pragma("unroll") for (int mb = 0; mb < 2; ++mb)                                  \
  _Pragma("unroll") for (int kh = 0; kh < 2; ++kh)                                  \
    afr[mb][kh] = frag_ld8(cur, wr * 128 + (H) * 64 + mb * 32 + (lane & 31),        \
                           kh * 64 + ((lane >> 5) << 5));

#define LD_B(H)                                                                     \
  _Pragma("unroll") for (int kh = 0; kh < 2; ++kh)                                  \
    bfr[(H)][kh] = frag_ld8(cur + ABUF, wc * 64 + (H) * 32 + (lane & 31),           \
                            kh * 64 + ((lane >> 5) << 5));

#define ST_A(HALF, KT)                                                              \
  stage_chunk(A, brow, (KT) * BKB, chA(HALF, wave * 2), lane, nxt);                 \
  stage_chunk(A, brow, (KT) * BKB, chA(HALF, wave * 2 + 1), lane, nxt);

#define ST_B(HALF, KT)                                                              \
  stage_chunk(Bt, bcol, (KT) * BKB, chB(HALF, wave * 2), lane, nxt + ABUF);         \
  stage_chunk(Bt, bcol, (KT) * BKB, chB(HALF, wave * 2 + 1), lane, nxt + ABUF);

#define MFMA_Q(MH, NB)                                                              \
  asm volatile("s_waitcnt lgkmcnt(0)" ::: "memory");                                \
  __builtin_amdgcn_sched_barrier(0);                                                \
  __builtin_amdgcn_s_setprio(1);                                                    \
  _Pragma("unroll") for (int mb = 0; mb < 2; ++mb)                                  \
  _Pragma("unroll") for (int kh = 0; kh < 2; ++kh)                                  \
    acc[(MH) * 2 + mb][NB] = __builtin_amdgcn_mfma_scale_f32_32x32x64_f8f6f4(       \
        afr[mb][kh], bfr[NB][kh], acc[(MH) * 2 + mb][NB], 0, 0, 0, 0x7F, 0, 0x7F);  \
  __builtin_amdgcn_s_setprio(0);

#define VMC(N) asm volatile("s_waitcnt vmcnt(" #N ")" ::: "memory");
#define LGKM0 asm volatile("s_waitcnt lgkmcnt(0)" ::: "memory");
#define BARR                                                                        \
  asm volatile("s_barrier" ::: "memory");                                           \
  __builtin_amdgcn_sched_barrier(0);

__global__ __launch_bounds__(512, 2)
void k_gemm(const unsigned char* __restrict__ A, const unsigned char* __restrict__ Bt,
            const float* __restrict__ benc, bf16* __restrict__ C) {
  extern __shared__ char lds[];
  int tid = threadIdx.x;
  int wave = tid >> 6;
  int lane = tid & 63;
  int wr = wave >> 2;          // 0..1, 128 rows each
  int wc = wave & 3;           // 0..3, 64 cols each

  // XCD-grouped bijective remap (512 blocks, 512%8==0)
  int d = blockIdx.x;                  // 0..511
  int lw = (d & 7) * 64 + (d >> 3);
  int q = lw >> 2;                     // col panel 0..127
  int p = lw & 3;                      // row block 0..3
  size_t brow = (size_t)p * BM;
  size_t bcol = (size_t)q * BN;

  f32x16 acc[4][2] = {};
  i32x8 afr[2][2];
  i32x8 bfr[2][2];

  // prologue: stage tile 0 (order B0,A0,B1,A1); publish B0,A0; barrier.
  {
    char* nxt = lds;
    ST_B(0, 0) ST_A(0, 0) ST_B(1, 0) ST_A(1, 0)
  }
  VMC(4)
  BARR

#pragma unroll 1
  for (int u = 0; u < NT - 1; ++u) {
    char* cur = lds + (u & 1) * BUFSZ;
    char* nxt = lds + ((u + 1) & 1) * BUFSZ;
    int k1 = u + 1;
    // q0: read A-h0, B-n0; stage B0(u+1); VMC(4) publishes B1(u) for q1
    LD_A(0) LD_B(0)
    ST_B(0, k1)
    VMC(4)
    BARR
    MFMA_Q(0, 0)
    // q1: read B-n1; stage A0(u+1); VMC(4) publishes A1(u) for q23
    LD_B(1)
    ST_A(0, k1)
    VMC(4)
    BARR
    MFMA_Q(0, 1)
    // q23: read A-h1; stage B1,A1(u+1); VMC(4) publishes B0,A0(u+1); lgkm drained pre-barrier
    LD_A(1)
    ST_B(1, k1) ST_A(1, k1)
    VMC(4)
    LGKM0
    BARR
    MFMA_Q(1, 1)
    MFMA_Q(1, 0)
  }

  // tail tile NT-1 (no staging); entry outstanding: B1(L),A1(L)
  {
    char* cur = lds + ((NT - 1) & 1) * BUFSZ;
    LD_A(0) LD_B(0)
    VMC(2)
    BARR
    MFMA_Q(0, 0)
    LD_B(1)
    VMC(0)
    BARR
    MFMA_Q(0, 1)
    LD_A(1)
    LGKM0
    BARR
    MFMA_Q(1, 1)
    MFMA_Q(1, 0)
  }

  // epilogue: 32x32 C/D layout col=lane&31, row=(reg&3)+8*(reg>>2)+4*(lane>>5); descale 1/16
#pragma unroll
  for (int nb = 0; nb < 2; ++nb) {
    size_t col = bcol + wc * 64 + nb * 32 + (lane & 31);
    float be = benc[col];
#pragma unroll
    for (int MB = 0; MB < 4; ++MB) {
      size_t row0 = brow + wr * 128 + MB * 32 + ((lane >> 5) << 2);
#pragma unroll
      for (int reg = 0; reg < 16; ++reg) {
        size_t row = row0 + (reg & 3) + ((reg >> 2) << 3);
        C[row * NFEAT + col] = (bf16)(acc[MB][nb][reg] * 0.0625f + be);
      }
    }
  }
}

// ---------------- per-row candidate extraction from bf16 pre ----------------
__global__ void k_topk(const unsigned short* __restrict__ pre, int* __restrict__ cand_idx,
                       int* __restrict__ cand_cnt) {
  __shared__ int hist[8192];   // 13-bit bins of 16-bit monotonic code
  __shared__ int csum[256];
  __shared__ int sBstar;
  __shared__ int scount;
  int b = blockIdx.x;
  int t = threadIdx.x;
  const unsigned short* row = pre + (size_t)b * NFEAT;
  for (int i = t; i < 8192; i += 256) hist[i] = 0;
  if (t == 0) scount = 0;
  __syncthreads();

  for (int i = (t << 3); i < NFEAT; i += 2048) {
    uint4 v = *reinterpret_cast<const uint4*>(row + i);
#pragma unroll
    for (int j = 0; j < 4; ++j) {
      unsigned w = (&v.x)[j];
      atomicAdd(&hist[mono16(w & 0xFFFFu) >> 3], 1);
      atomicAdd(&hist[mono16(w >> 16) >> 3], 1);
    }
  }
  __syncthreads();

  int s = 0;
  for (int i = 0; i < 32; ++i) s += hist[t * 32 + i];
  csum[t] = s;
  __syncthreads();
  int suff = 0;
  for (int j = t + 1; j < 256; ++j) suff += csum[j];
  if (suff < CAND_TARGET && suff + s >= CAND_TARGET) {
    int acc = suff;
    int bstar = t * 32;
    for (int i = 31; i >= 0; --i) {
      acc += hist[t * 32 + i];
      if (acc >= CAND_TARGET) { bstar = t * 32 + i; break; }
    }
    sBstar = bstar;
  }
  __syncthreads();
  int Bstar = sBstar;
  int* cidx = cand_idx + b * CAND_CAP;

  for (int i = (t << 3); i < NFEAT; i += 2048) {
    uint4 v = *reinterpret_cast<const uint4*>(row + i);
#pragma unroll
    for (int j = 0; j < 4; ++j) {
      unsigned w = (&v.x)[j];
      int b0 = (int)(mono16(w & 0xFFFFu) >> 3);
      int b1 = (int)(mono16(w >> 16) >> 3);
      if (b0 >= Bstar) { int p2 = atomicAdd(&scount, 1); if (p2 < CAND_CAP) cidx[p2] = i + j * 2; }
      if (b1 >= Bstar) { int p2 = atomicAdd(&scount, 1); if (p2 < CAND_CAP) cidx[p2] = i + j * 2 + 1; }
    }
  }
  __syncthreads();
  if (t == 0) cand_cnt[b] = (scount < CAND_CAP) ? scount : CAND_CAP;
}

// ---------------- fp32 refine + exact top-32 + scatter + decode + mse partial ----------------
// (coeffs zeroed beforehand by hipMemsetAsync)
__global__ void k_refine(const float* __restrict__ x,
                         const float* __restrict__ Venc,
                         const float* __restrict__ Wenc,
                         const float* __restrict__ benc,
                         const float* __restrict__ Vdec,
                         const float* __restrict__ Wdec,
                         const float* __restrict__ bias,
                         const int* __restrict__ cand_idx,
                         const int* __restrict__ cand_cnt,
                         float* __restrict__ recon,
                         float* __restrict__ coeffs,
                         float* __restrict__ msepart) {
  __shared__ float rval[CAND_CAP];
  __shared__ int ridx[CAND_CAP];
  __shared__ float selv[KSEL];
  __shared__ int seli[KSEL];
  __shared__ float Vd[KSEL][DK];
  __shared__ float Wd[KSEL][DV];
  __shared__ float red[256];

  int b = blockIdx.x;
  int t = threadIdx.x;
  int wave = t >> 6;
  int lane = t & 63;

  const float* xr = x + (size_t)b * DD;

  // per-lane register cache of x: xreg[kk] = x[b][kk][lane] (lane = v)
  float xreg[DK];
#pragma unroll
  for (int kk = 0; kk < DK; ++kk)
    xreg[kk] = xr[kk * DV + lane];

  int c = cand_cnt[b];
  if (c > CAND_CAP) c = CAND_CAP;
  for (int i = t; i < c; i += 256) ridx[i] = cand_idx[b * CAND_CAP + i];
  __syncthreads();

  // exact fp32 pre per candidate: V row via SGPR (uniform), x in regs, W coalesced
  for (int j = wave; j < c; j += 4) {
    int fi = __builtin_amdgcn_readfirstlane(ridx[j]);
    const float* vr = Venc + (size_t)fi * DK;
    float w = Wenc[(size_t)fi * DV + lane];
    float a0 = 0.f, a1 = 0.f, a2 = 0.f, a3 = 0.f;
#pragma unroll
    for (int kk = 0; kk < DK; kk += 4) {
      a0 = fmaf(xreg[kk + 0], vr[kk + 0], a0);
      a1 = fmaf(xreg[kk + 1], vr[kk + 1], a1);
      a2 = fmaf(xreg[kk + 2], vr[kk + 2], a2);
      a3 = fmaf(xreg[kk + 3], vr[kk + 3], a3);
    }
    float p2 = ((a0 + a1) + (a2 + a3)) * w;
#pragma unroll
    for (int off = 1; off < 64; off <<= 1) p2 += __shfl_xor(p2, off);
    if (lane == 0) rval[j] = p2 + benc[fi];
  }
  __syncthreads();

  // exact rank among candidates (tie-break: lower feature index first, matches np)
  for (int t2 = t; t2 < c; t2 += 256) {
    float v = rval[t2];
    int fi = ridx[t2];
    int rank = 0;
    for (int j = 0; j < c; ++j) {
      float vj = rval[j];
      if (vj > v || (vj == v && ridx[j] < fi)) ++rank;
    }
    if (rank < KSEL) { selv[rank] = v; seli[rank] = fi; }
  }
  __syncthreads();

  if (t < KSEL) {
    float v = fmaxf(selv[t], 0.f);
    selv[t] = v;
    coeffs[(size_t)b * NFEAT + seli[t]] = v;
  }
  __syncthreads();

  for (int i = t; i < KSEL * DK; i += 256) {
    int s = i >> 6, e = i & 63;
    Vd[s][e] = Vdec[(size_t)seli[s] * DK + e];
    Wd[s][e] = Wdec[(size_t)seli[s] * DV + e];
  }
  __syncthreads();

  // decode: thread owns 16 contiguous recon elems; Wd consumed as float4
  int k = t >> 2;
  int vb = (t & 3) << 4;
  float4 r4[4];
#pragma unroll
  for (int g = 0; g < 4; ++g)
    r4[g] = *reinterpret_cast<const float4*>(bias + k * DV + vb + g * 4);
#pragma unroll
  for (int s = 0; s < KSEL; ++s) {
    float a = selv[s] * Vd[s][k];
    const float4* wrow = reinterpret_cast<const float4*>(&Wd[s][vb]);
#pragma unroll
    for (int g = 0; g < 4; ++g) {
      float4 wv = wrow[g];
      r4[g].x = fmaf(a, wv.x, r4[g].x);
      r4[g].y = fmaf(a, wv.y, r4[g].y);
      r4[g].z = fmaf(a, wv.z, r4[g].z);
      r4[g].w = fmaf(a, wv.w, r4[g].w);
    }
  }
  float m = 0.f;
  float* ro = recon + (size_t)b * DD + k * DV + vb;
#pragma unroll
  for (int g = 0; g < 4; ++g) {
    float4 xv = *reinterpret_cast<const float4*>(xr + k * DV + vb + g * 4);
    float dx = r4[g].x - xv.x, dy = r4[g].y - xv.y;
    float dz = r4[g].z - xv.z, dw = r4[g].w - xv.w;
    m = fmaf(dx, dx, m); m = fmaf(dy, dy, m);
    m = fmaf(dz, dz, m); m = fmaf(dw, dw, m);
    *reinterpret_cast<float4*>(ro + g * 4) = r4[g];
  }
  red[t] = m;
  __syncthreads();
  for (int s2 = 128; s2 > 0; s2 >>= 1) {
    if (t < s2) red[t] += red[t + s2];
    __syncthreads();
  }
  if (t == 0) msepart[b] = red[0];
}

__global__ void k_mse(const float* __restrict__ msepart, float* __restrict__ out) {
  __shared__ float red[256];
  int t = threadIdx.x;
  float s = 0.f;
  for (int i = t; i < BATCH; i += 256) s += msepart[i];
  red[t] = s;
  __syncthreads();
  for (int k = 128; k > 0; k >>= 1) {
    if (t < k) red[t] += red[t + k];
    __syncthreads();
  }
  if (t == 0) out[0] = red[0] / (float)((size_t)BATCH * DD);
}

extern "C" void kernel_launch(void* const* d_in, const int* in_sizes, int n_in,
                              void* d_out, int out_size, void* d_ws, size_t ws_size,
                              hipStream_t stream) {
  const float* x    = (const float*)d_in[0];
  const float* Venc = (const float*)d_in[1];
  const float* Wenc = (const float*)d_in[2];
  const float* benc = (const float*)d_in[3];
  const float* Vdec = (const float*)d_in[4];
  const float* Wdec = (const float*)d_in[5];
  const float* bias = (const float*)d_in[6];

  float* out = (float*)d_out;
  float* recon  = out;                                   // [1024, 4096]
  float* coeffs = out + (size_t)BATCH * DD;              // [1024, 32768]
  float* mse    = coeffs + (size_t)BATCH * NFEAT;        // [1]

  char* wsp = (char*)d_ws;
  unsigned char* xb8 = (unsigned char*)wsp;   wsp += (size_t)BATCH * DD;
  unsigned char* Menc8 = (unsigned char*)wsp; wsp += (size_t)NFEAT * DD;
  int* cand_idx = (int*)wsp;                  wsp += (size_t)BATCH * CAND_CAP * sizeof(int);
  int* cand_cnt = (int*)wsp;                  wsp += (size_t)BATCH * sizeof(int);
  float* msepart = (float*)wsp;               wsp += (size_t)BATCH * sizeof(float);

  bf16* pre = (bf16*)coeffs;  // reuse coeffs region as bf16 pre scratch

  hipFuncSetAttribute((const void*)k_gemm, hipFuncAttributeMaxDynamicSharedMemorySize,
                      GEMM_LDS);

  k_convert_x<<<(BATCH * DD) / (256 * 16), 256, 0, stream>>>(x, xb8, BATCH * DD);
  k_build_menc<<<NFEAT, 256, 0, stream>>>(Venc, Wenc, Menc8);
  k_gemm<<<(BATCH / BM) * (NFEAT / BN), 512, GEMM_LDS, stream>>>(xb8, Menc8, benc, pre);
  k_topk<<<BATCH, 256, 0, stream>>>((const unsigned short*)pre, cand_idx, cand_cnt);
  hipMemsetAsync(coeffs, 0, (size_t)BATCH * NFEAT * sizeof(float), stream);
  k_refine<<<BATCH, 256, 0, stream>>>(x, Venc, Wenc, benc, Vdec, Wdec, bias,
                                      cand_idx, cand_cnt, recon, coeffs, msepart);
  k_mse<<<1, 256, 0, stream>>>(msepart, mse);
}